// Round 8
// baseline (210.371 us; speedup 1.0000x reference)
//
#include <hip/hip_runtime.h>
#include <hip/hip_bf16.h>

#define NEG_SLOPE 0.2f

typedef short s16x8 __attribute__((ext_vector_type(8)));
typedef float f32x4 __attribute__((ext_vector_type(4)));

__device__ __forceinline__ unsigned short f2bf(float f) {
    unsigned int u = __float_as_uint(f);
    u += 0x7FFFu + ((u >> 16) & 1u);   // RNE
    return (unsigned short)(u >> 16);
}

// ---------------- CSR build ----------------

__global__ void zero_kernel(int* __restrict__ p, int count) {
    int i = blockIdx.x * blockDim.x + threadIdx.x;
    if (i < count) p[i] = 0;
}

__global__ void count_kernel(const int* __restrict__ ei, int e, int n, int* __restrict__ cnt) {
    int i = blockIdx.x * blockDim.x + threadIdx.x;
    int total = e + n;
    if (i >= total) return;
    int dst = (i < e) ? ei[e + i] : (i - e);
    atomicAdd(&cnt[dst], 1);
}

__global__ __launch_bounds__(256) void scanA_kernel(const int* __restrict__ cnt, int* __restrict__ bsum, int n) {
    int b = blockIdx.x, t = threadIdx.x;
    int base = b * 1024;
    int s = 0;
#pragma unroll
    for (int q = 0; q < 4; ++q) {
        int i = base + t + q * 256;
        if (i < n) s += cnt[i];
    }
    int lane = t & 63, wid = t >> 6;
#pragma unroll
    for (int off = 32; off; off >>= 1) s += __shfl_xor(s, off, 64);
    __shared__ int ws[4];
    if (lane == 0) ws[wid] = s;
    __syncthreads();
    if (t == 0) bsum[b] = ws[0] + ws[1] + ws[2] + ws[3];
}

__global__ __launch_bounds__(64) void scanB_kernel(const int* __restrict__ bsum, int* __restrict__ bbase,
                                                   int* __restrict__ rowptr, int nb, int n) {
    int t = threadIdx.x;
    int carry = 0;
    for (int c = 0; c < nb; c += 64) {
        int i = c + t;
        int v = (i < nb) ? bsum[i] : 0;
        int incl = v;
#pragma unroll
        for (int off = 1; off < 64; off <<= 1) {
            int u = __shfl_up(incl, off, 64);
            if (t >= off) incl += u;
        }
        if (i < nb) bbase[i] = carry + incl - v;
        carry += __shfl(incl, 63, 64);
    }
    if (t == 0) rowptr[n] = carry;
}

__global__ __launch_bounds__(256) void scanC_kernel(const int* __restrict__ cnt, const int* __restrict__ bbase,
                                                    int* __restrict__ rowptr, int n) {
    int b = blockIdx.x, t = threadIdx.x;
    int idx = b * 1024 + t * 4;
    int4 v = make_int4(0, 0, 0, 0);
    if (idx + 3 < n) v = *(const int4*)(cnt + idx);
    else {
        if (idx < n)     v.x = cnt[idx];
        if (idx + 1 < n) v.y = cnt[idx + 1];
        if (idx + 2 < n) v.z = cnt[idx + 2];
        if (idx + 3 < n) v.w = cnt[idx + 3];
    }
    int s0 = v.x, s1 = s0 + v.y, s2 = s1 + v.z, s3 = s2 + v.w;
    int tot = s3;
    int lane = t & 63, wid = t >> 6;
    int incl = tot;
#pragma unroll
    for (int off = 1; off < 64; off <<= 1) {
        int u = __shfl_up(incl, off, 64);
        if (lane >= off) incl += u;
    }
    __shared__ int wtot[4];
    if (lane == 63) wtot[wid] = incl;
    __syncthreads();
    int woff = 0;
    for (int w = 0; w < wid; ++w) woff += wtot[w];
    int ex = incl - tot + woff + bbase[b];
    if (idx < n)     rowptr[idx]     = ex;
    if (idx + 1 < n) rowptr[idx + 1] = ex + s0;
    if (idx + 2 < n) rowptr[idx + 2] = ex + s1;
    if (idx + 3 < n) rowptr[idx + 3] = ex + s2;
}

__global__ void fill_kernel(const int* __restrict__ ei, int e, int n,
                            const int* __restrict__ rowptr, int* __restrict__ fillc,
                            int* __restrict__ colsrc, int* __restrict__ coldst) {
    int i = blockIdx.x * blockDim.x + threadIdx.x;
    int total = e + n;
    if (i >= total) return;
    int src, dst;
    if (i < e) { src = ei[i]; dst = ei[e + i]; }
    else       { src = i - e; dst = i - e; }
    int pos = atomicAdd(&fillc[dst], 1);
    int p = rowptr[dst] + pos;
    colsrc[p] = src;
    coldst[p] = dst;
}

// ---------------- per-edge softmax weights (unnormalized) ----------------

__global__ __launch_bounds__(256) void weight8_kernel(const int* __restrict__ colsrc,
                                                      const int* __restrict__ coldst,
                                                      const float* __restrict__ as,
                                                      const float* __restrict__ ad,
                                                      float* __restrict__ wbuf, int en) {
    int i = blockIdx.x * blockDim.x + threadIdx.x;
    if (i >= en) return;
    int s = colsrc[i], d = coldst[i];
    const float4* ap = (const float4*)(as + (size_t)s * 8);
    const float4* dp = (const float4*)(ad + (size_t)d * 8);
    float4 a0 = ap[0], a1 = ap[1], d0 = dp[0], d1 = dp[1];
    float evs[8] = {a0.x + d0.x, a0.y + d0.y, a0.z + d0.z, a0.w + d0.w,
                    a1.x + d1.x, a1.y + d1.y, a1.z + d1.z, a1.w + d1.w};
    float o[8];
#pragma unroll
    for (int h = 0; h < 8; ++h) {
        float ev = evs[h];
        ev = (ev > 0.f) ? ev : NEG_SLOPE * ev;
        o[h] = __expf(ev);
    }
    float4* wp = (float4*)(wbuf + (size_t)i * 8);
    wp[0] = make_float4(o[0], o[1], o[2], o[3]);
    wp[1] = make_float4(o[4], o[5], o[6], o[7]);
}

__global__ __launch_bounds__(256) void weight1_kernel(const int* __restrict__ colsrc,
                                                      const int* __restrict__ coldst,
                                                      const float* __restrict__ as,
                                                      const float* __restrict__ ad,
                                                      float* __restrict__ wbuf, int en) {
    int i = blockIdx.x * blockDim.x + threadIdx.x;
    if (i >= en) return;
    float ev = as[colsrc[i]] + ad[coldst[i]];
    ev = (ev > 0.f) ? ev : NEG_SLOPE * ev;
    wbuf[i] = __expf(ev);
}

// ---------------- prep: fragment-ordered bf16 [W | W@a] ----------------

__global__ __launch_bounds__(256) void prep_w_kernel(const float* __restrict__ W,
                                                     const float* __restrict__ as_v,
                                                     const float* __restrict__ ad_v,
                                                     int H, unsigned short* __restrict__ Wf) {
    int kt = blockIdx.x;   // 0..3
    int t = threadIdx.x;
    for (int task = t; task < 9 * 64; task += 256) {
        int ct = task / 64, l = task & 63;
        int kbase = kt * 32 + (l >> 4) * 8;
        int c = l & 15;
        unsigned short o[8];
        if (ct < 8) {
            int col = ct * 16 + c;
#pragma unroll
            for (int j = 0; j < 8; ++j) o[j] = f2bf(W[(size_t)(kbase + j) * 128 + col]);
        } else {
#pragma unroll
            for (int j = 0; j < 8; ++j) {
                float s = 0.f;
                if (H == 8) {
                    const float* a = (c < 8) ? as_v : ad_v;
                    int hh = c & 7;
                    for (int m = 0; m < 16; ++m)
                        s += W[(size_t)(kbase + j) * 128 + hh * 16 + m] * a[hh * 16 + m];
                } else if (c < 2) {
                    const float* a = (c == 0) ? as_v : ad_v;
                    for (int m = 0; m < 128; ++m)
                        s += W[(size_t)(kbase + j) * 128 + m] * a[m];
                }
                o[j] = f2bf(s);
            }
        }
        *(uint4*)&Wf[(((size_t)kt * 9 + ct) * 64 + l) * 8] = *(uint4*)o;
    }
}

// ---------------- MFMA GEMM: [h | alpha] = X @ [W | Wa] ----------------

template <int H, bool INBF16>
__global__ __launch_bounds__(256) void gemm_mfma_kernel(const void* __restrict__ Xv,
                                                        const unsigned short* __restrict__ Wf,
                                                        unsigned short* __restrict__ Ob,
                                                        float* __restrict__ as_out,
                                                        float* __restrict__ ad_out, int n) {
    __shared__ unsigned short lds[26624];   // 8192 A + 18432 W
    int tid = threadIdx.x;
    int row0 = blockIdx.x * 64;

    {
        const uint4* src = (const uint4*)Wf;
        uint4* dst = (uint4*)&lds[8192];
#pragma unroll
        for (int i = 0; i < 9; ++i) dst[tid + 256 * i] = src[tid + 256 * i];
    }
#pragma unroll
    for (int q = 0; q < 4; ++q) {
        int task = tid + q * 256;
        int r = task >> 4, kc = task & 15;
        int gr = row0 + r;
        uint4 val = make_uint4(0, 0, 0, 0);
        if (gr < n) {
            if (INBF16) {
                val = *(const uint4*)((const unsigned short*)Xv + (size_t)gr * 128 + kc * 8);
            } else {
                const float4* xp = (const float4*)((const float*)Xv + (size_t)gr * 128 + kc * 8);
                float4 x0 = xp[0], x1 = xp[1];
                unsigned short o[8] = {f2bf(x0.x), f2bf(x0.y), f2bf(x0.z), f2bf(x0.w),
                                       f2bf(x1.x), f2bf(x1.y), f2bf(x1.z), f2bf(x1.w)};
                val = *(uint4*)o;
            }
        }
        int w = r >> 4, kt = kc >> 2, lane = ((kc & 3) << 4) + (r & 15);
        *(uint4*)&lds[(size_t)(((w * 4 + kt) * 64) + lane) * 8] = val;
    }
    __syncthreads();

    int w = tid >> 6, l = tid & 63;
    f32x4 acc[9];
#pragma unroll
    for (int ct = 0; ct < 9; ++ct) acc[ct] = (f32x4){0.f, 0.f, 0.f, 0.f};
#pragma unroll
    for (int kt = 0; kt < 4; ++kt) {
        s16x8 a = *(s16x8*)&lds[(size_t)((w * 4 + kt) * 64 + l) * 8];
#pragma unroll
        for (int ct = 0; ct < 9; ++ct) {
            s16x8 b = *(s16x8*)&lds[8192 + (size_t)((kt * 9 + ct) * 64 + l) * 8];
            acc[ct] = __builtin_amdgcn_mfma_f32_16x16x32_bf16(a, b, acc[ct], 0, 0, 0);
        }
    }

    int c = l & 15, rgrp = l >> 4;
    int rowb = row0 + w * 16 + rgrp * 4;
#pragma unroll
    for (int reg = 0; reg < 4; ++reg) {
        int row = rowb + reg;
        if (row < n) {
#pragma unroll
            for (int ct = 0; ct < 8; ++ct)
                Ob[(size_t)row * 128 + ct * 16 + c] = f2bf(acc[ct][reg]);
            float av = acc[8][reg];
            if (H == 8) {
                if (c < 8) as_out[(size_t)row * 8 + c] = av;
                else       ad_out[(size_t)row * 8 + (c - 8)] = av;
            } else {
                if (c == 0)      as_out[row] = av;
                else if (c == 1) ad_out[row] = av;
            }
        }
    }
}

// ---------------- aggregation: 1 node per 16-lane group, weights prestreamed ----------------
// block 256 = 16 nodes; lane cl owns channels cl*8..cl*8+7. No cross-lane reduce.

template <int H, int OBF>
__global__ __launch_bounds__(256) void agg_kernel(const int* __restrict__ rowptr,
                                                  const int* __restrict__ colsrc,
                                                  const float* __restrict__ wbuf,
                                                  const unsigned short* __restrict__ hb,
                                                  const float* __restrict__ bias,
                                                  void* __restrict__ outv, int n) {
    int tid = threadIdx.x;
    int node = blockIdx.x * 16 + (tid >> 4);
    int cl = tid & 15;
    if (node >= n) return;
    int beg = rowptr[node];
    int end = rowptr[node + 1];
    int head = (H == 8) ? (cl >> 1) : 0;

    float acc[8];
#pragma unroll
    for (int c = 0; c < 8; ++c) acc[c] = 0.f;
    float den = 0.f;

#pragma unroll 2
    for (int i = beg; i < end; ++i) {
        int s = colsrc[i];
        float wgt = wbuf[(size_t)i * H + head];
        den += wgt;
        uint4 a = *(const uint4*)(hb + (size_t)s * 128 + cl * 8);
        unsigned int u[4] = {a.x, a.y, a.z, a.w};
#pragma unroll
        for (int k = 0; k < 4; ++k) {
            float lo = __uint_as_float(u[k] << 16);
            float hi = __uint_as_float(u[k] & 0xffff0000u);
            acc[2 * k]     += wgt * lo;
            acc[2 * k + 1] += wgt * hi;
        }
    }

    float inv = 1.0f / den;
    float r[8];
#pragma unroll
    for (int k = 0; k < 8; ++k) {
        r[k] = acc[k] * inv + bias[cl * 8 + k];
        if (OBF) r[k] = (r[k] > 0.f) ? r[k] : expm1f(r[k]);  // ELU (layer 1)
    }
    if (OBF) {
        unsigned short o[8];
#pragma unroll
        for (int k = 0; k < 8; ++k) o[k] = f2bf(r[k]);
        *(uint4*)((unsigned short*)outv + (size_t)node * 128 + cl * 8) = *(uint4*)o;
    } else {
        float4* p = (float4*)((float*)outv + (size_t)node * 128 + cl * 8);
        p[0] = make_float4(r[0], r[1], r[2], r[3]);
        p[1] = make_float4(r[4], r[5], r[6], r[7]);
    }
}

// ---------------- launch ----------------

extern "C" void kernel_launch(void* const* d_in, const int* in_sizes, int n_in,
                              void* d_out, int out_size, void* d_ws, size_t ws_size,
                              hipStream_t stream) {
    const float* x    = (const float*)d_in[0];
    const int*   ei   = (const int*)d_in[1];
    const float* W1   = (const float*)d_in[2];
    const float* a_s1 = (const float*)d_in[3];
    const float* a_d1 = (const float*)d_in[4];
    const float* b1   = (const float*)d_in[5];
    const float* W2   = (const float*)d_in[6];
    const float* a_s2 = (const float*)d_in[7];
    const float* a_d2 = (const float*)d_in[8];
    const float* b2   = (const float*)d_in[9];

    const int n  = in_sizes[0] / 128;
    const int e  = in_sizes[1] / 2;
    const int en = e + n;
    const int nb = (n + 1023) / 1024;

    char* ws = (char*)d_ws;
    size_t off = 0;
    auto alloc = [&](size_t bytes) -> void* {
        void* p = ws + off;
        off += (bytes + 255) & ~(size_t)255;
        return p;
    };
    unsigned short* hb   = (unsigned short*)alloc((size_t)n * 128 * 2);
    unsigned short* hmid = (unsigned short*)alloc((size_t)n * 128 * 2);
    float* as1    = (float*)alloc((size_t)n * 8 * 4);
    float* ad1    = (float*)alloc((size_t)n * 8 * 4);
    float* as2    = (float*)alloc((size_t)n * 4);
    float* ad2    = (float*)alloc((size_t)n * 4);
    int*   cnt    = (int*)alloc((size_t)n * 4 * 2);
    int*   fillc  = cnt + n;
    int*   rowptr = (int*)alloc((size_t)(n + 1) * 4);
    int*   colsrc = (int*)alloc((size_t)en * 4);
    int*   coldst = (int*)alloc((size_t)en * 4);
    int*   bsum   = (int*)alloc((size_t)nb * 4);
    int*   bbase  = (int*)alloc((size_t)nb * 4);
    unsigned short* Wf1 = (unsigned short*)alloc(4 * 9 * 64 * 8 * 2);
    unsigned short* Wf2 = (unsigned short*)alloc(4 * 9 * 64 * 8 * 2);
    float* wbuf   = (float*)alloc((size_t)en * 8 * 4);   // reused by layer 2

    // CSR build (same graph both layers)
    zero_kernel<<<(2 * n + 255) / 256, 256, 0, stream>>>(cnt, 2 * n);
    count_kernel<<<(en + 255) / 256, 256, 0, stream>>>(ei, e, n, cnt);
    scanA_kernel<<<nb, 256, 0, stream>>>(cnt, bsum, n);
    scanB_kernel<<<1, 64, 0, stream>>>(bsum, bbase, rowptr, nb, n);
    scanC_kernel<<<nb, 256, 0, stream>>>(cnt, bbase, rowptr, n);
    fill_kernel<<<(en + 255) / 256, 256, 0, stream>>>(ei, e, n, rowptr, fillc, colsrc, coldst);

    // weight prep (fragment-ordered bf16 [W | W@a])
    prep_w_kernel<<<4, 256, 0, stream>>>(W1, a_s1, a_d1, 8, Wf1);
    prep_w_kernel<<<4, 256, 0, stream>>>(W2, a_s2, a_d2, 1, Wf2);

    int gemm_grid = (n + 63) / 64;
    int node_grid = (n + 15) / 16;
    int edge_grid = (en + 255) / 256;

    // layer 1
    gemm_mfma_kernel<8, false><<<gemm_grid, 256, 0, stream>>>(x, Wf1, hb, as1, ad1, n);
    weight8_kernel<<<edge_grid, 256, 0, stream>>>(colsrc, coldst, as1, ad1, wbuf, en);
    agg_kernel<8, 1><<<node_grid, 256, 0, stream>>>(rowptr, colsrc, wbuf, hb, b1, hmid, n);

    // layer 2
    gemm_mfma_kernel<1, true><<<gemm_grid, 256, 0, stream>>>(hmid, Wf2, hb, as2, ad2, n);
    weight1_kernel<<<edge_grid, 256, 0, stream>>>(colsrc, coldst, as2, ad2, wbuf, en);
    agg_kernel<1, 0><<<node_grid, 256, 0, stream>>>(rowptr, colsrc, wbuf, hb, b2, d_out, n);

    (void)n_in; (void)out_size; (void)ws_size;
}

// Round 9
// 166.086 us; speedup vs baseline: 1.2666x; 1.2666x over previous
//
#include <hip/hip_runtime.h>
#include <hip/hip_bf16.h>

#define NEG_SLOPE 0.2f

typedef short s16x8 __attribute__((ext_vector_type(8)));
typedef float f32x4 __attribute__((ext_vector_type(4)));

__device__ __forceinline__ unsigned short f2bf(float f) {
    unsigned int u = __float_as_uint(f);
    u += 0x7FFFu + ((u >> 16) & 1u);   // RNE
    return (unsigned short)(u >> 16);
}

// ---------------- CSR build ----------------

__global__ void zero_kernel(int* __restrict__ p, int count) {
    int i = blockIdx.x * blockDim.x + threadIdx.x;
    if (i < count) p[i] = 0;
}

// pos[i] = arrival order of edge i at its destination; cnt[dst] counts in-degree.
__global__ void assign_kernel(const int* __restrict__ ei, int e, int n,
                              int* __restrict__ cnt, int* __restrict__ pos) {
    int i = blockIdx.x * blockDim.x + threadIdx.x;
    int total = e + n;
    if (i >= total) return;
    int dst = (i < e) ? ei[e + i] : (i - e);
    pos[i] = atomicAdd(&cnt[dst], 1);
}

__global__ __launch_bounds__(256) void scanA_kernel(const int* __restrict__ cnt, int* __restrict__ bsum, int n) {
    int b = blockIdx.x, t = threadIdx.x;
    int base = b * 1024;
    int s = 0;
#pragma unroll
    for (int q = 0; q < 4; ++q) {
        int i = base + t + q * 256;
        if (i < n) s += cnt[i];
    }
    int lane = t & 63, wid = t >> 6;
#pragma unroll
    for (int off = 32; off; off >>= 1) s += __shfl_xor(s, off, 64);
    __shared__ int ws[4];
    if (lane == 0) ws[wid] = s;
    __syncthreads();
    if (t == 0) bsum[b] = ws[0] + ws[1] + ws[2] + ws[3];
}

__global__ __launch_bounds__(64) void scanB_kernel(const int* __restrict__ bsum, int* __restrict__ bbase,
                                                   int* __restrict__ rowptr, int nb, int n) {
    int t = threadIdx.x;
    int carry = 0;
    for (int c = 0; c < nb; c += 64) {
        int i = c + t;
        int v = (i < nb) ? bsum[i] : 0;
        int incl = v;
#pragma unroll
        for (int off = 1; off < 64; off <<= 1) {
            int u = __shfl_up(incl, off, 64);
            if (t >= off) incl += u;
        }
        if (i < nb) bbase[i] = carry + incl - v;
        carry += __shfl(incl, 63, 64);
    }
    if (t == 0) rowptr[n] = carry;
}

__global__ __launch_bounds__(256) void scanC_kernel(const int* __restrict__ cnt, const int* __restrict__ bbase,
                                                    int* __restrict__ rowptr, int n) {
    int b = blockIdx.x, t = threadIdx.x;
    int idx = b * 1024 + t * 4;
    int4 v = make_int4(0, 0, 0, 0);
    if (idx + 3 < n) v = *(const int4*)(cnt + idx);
    else {
        if (idx < n)     v.x = cnt[idx];
        if (idx + 1 < n) v.y = cnt[idx + 1];
        if (idx + 2 < n) v.z = cnt[idx + 2];
        if (idx + 3 < n) v.w = cnt[idx + 3];
    }
    int s0 = v.x, s1 = s0 + v.y, s2 = s1 + v.z, s3 = s2 + v.w;
    int tot = s3;
    int lane = t & 63, wid = t >> 6;
    int incl = tot;
#pragma unroll
    for (int off = 1; off < 64; off <<= 1) {
        int u = __shfl_up(incl, off, 64);
        if (lane >= off) incl += u;
    }
    __shared__ int wtot[4];
    if (lane == 63) wtot[wid] = incl;
    __syncthreads();
    int woff = 0;
    for (int w = 0; w < wid; ++w) woff += wtot[w];
    int ex = incl - tot + woff + bbase[b];
    if (idx < n)     rowptr[idx]     = ex;
    if (idx + 1 < n) rowptr[idx + 1] = ex + s0;
    if (idx + 2 < n) rowptr[idx + 2] = ex + s1;
    if (idx + 3 < n) rowptr[idx + 3] = ex + s2;
}

// place edge i at colsrc[rowptr[dst] + pos[i]] — no atomics, one random 4B write.
__global__ void place_kernel(const int* __restrict__ ei, const int* __restrict__ pos,
                             const int* __restrict__ rowptr, int e, int n,
                             int* __restrict__ colsrc) {
    int i = blockIdx.x * blockDim.x + threadIdx.x;
    int total = e + n;
    if (i >= total) return;
    int src, dst;
    if (i < e) { src = ei[i]; dst = ei[e + i]; }
    else       { src = i - e; dst = i - e; }
    colsrc[rowptr[dst] + pos[i]] = src;
}

// ---------------- prep: fragment-ordered bf16 [W | W@a] ----------------

__global__ __launch_bounds__(256) void prep_w_kernel(const float* __restrict__ W,
                                                     const float* __restrict__ as_v,
                                                     const float* __restrict__ ad_v,
                                                     int H, unsigned short* __restrict__ Wf) {
    int kt = blockIdx.x;   // 0..3
    int t = threadIdx.x;
    for (int task = t; task < 9 * 64; task += 256) {
        int ct = task / 64, l = task & 63;
        int kbase = kt * 32 + (l >> 4) * 8;
        int c = l & 15;
        unsigned short o[8];
        if (ct < 8) {
            int col = ct * 16 + c;
#pragma unroll
            for (int j = 0; j < 8; ++j) o[j] = f2bf(W[(size_t)(kbase + j) * 128 + col]);
        } else {
#pragma unroll
            for (int j = 0; j < 8; ++j) {
                float s = 0.f;
                if (H == 8) {
                    const float* a = (c < 8) ? as_v : ad_v;
                    int hh = c & 7;
                    for (int m = 0; m < 16; ++m)
                        s += W[(size_t)(kbase + j) * 128 + hh * 16 + m] * a[hh * 16 + m];
                } else if (c < 2) {
                    const float* a = (c == 0) ? as_v : ad_v;
                    for (int m = 0; m < 128; ++m)
                        s += W[(size_t)(kbase + j) * 128 + m] * a[m];
                }
                o[j] = f2bf(s);
            }
        }
        *(uint4*)&Wf[(((size_t)kt * 9 + ct) * 64 + l) * 8] = *(uint4*)o;
    }
}

// ---------------- MFMA GEMM: [h | alpha] = X @ [W | Wa] ----------------

template <int H, bool INBF16>
__global__ __launch_bounds__(256) void gemm_mfma_kernel(const void* __restrict__ Xv,
                                                        const unsigned short* __restrict__ Wf,
                                                        unsigned short* __restrict__ Ob,
                                                        float* __restrict__ as_out,
                                                        float* __restrict__ ad_out, int n) {
    __shared__ unsigned short lds[26624];   // 8192 A + 18432 W
    int tid = threadIdx.x;
    int row0 = blockIdx.x * 64;

    {
        const uint4* src = (const uint4*)Wf;
        uint4* dst = (uint4*)&lds[8192];
#pragma unroll
        for (int i = 0; i < 9; ++i) dst[tid + 256 * i] = src[tid + 256 * i];
    }
#pragma unroll
    for (int q = 0; q < 4; ++q) {
        int task = tid + q * 256;
        int r = task >> 4, kc = task & 15;
        int gr = row0 + r;
        uint4 val = make_uint4(0, 0, 0, 0);
        if (gr < n) {
            if (INBF16) {
                val = *(const uint4*)((const unsigned short*)Xv + (size_t)gr * 128 + kc * 8);
            } else {
                const float4* xp = (const float4*)((const float*)Xv + (size_t)gr * 128 + kc * 8);
                float4 x0 = xp[0], x1 = xp[1];
                unsigned short o[8] = {f2bf(x0.x), f2bf(x0.y), f2bf(x0.z), f2bf(x0.w),
                                       f2bf(x1.x), f2bf(x1.y), f2bf(x1.z), f2bf(x1.w)};
                val = *(uint4*)o;
            }
        }
        int w = r >> 4, kt = kc >> 2, lane = ((kc & 3) << 4) + (r & 15);
        *(uint4*)&lds[(size_t)(((w * 4 + kt) * 64) + lane) * 8] = val;
    }
    __syncthreads();

    int w = tid >> 6, l = tid & 63;
    f32x4 acc[9];
#pragma unroll
    for (int ct = 0; ct < 9; ++ct) acc[ct] = (f32x4){0.f, 0.f, 0.f, 0.f};
#pragma unroll
    for (int kt = 0; kt < 4; ++kt) {
        s16x8 a = *(s16x8*)&lds[(size_t)((w * 4 + kt) * 64 + l) * 8];
#pragma unroll
        for (int ct = 0; ct < 9; ++ct) {
            s16x8 b = *(s16x8*)&lds[8192 + (size_t)((kt * 9 + ct) * 64 + l) * 8];
            acc[ct] = __builtin_amdgcn_mfma_f32_16x16x32_bf16(a, b, acc[ct], 0, 0, 0);
        }
    }

    int c = l & 15, rgrp = l >> 4;
    int rowb = row0 + w * 16 + rgrp * 4;
#pragma unroll
    for (int reg = 0; reg < 4; ++reg) {
        int row = rowb + reg;
        if (row < n) {
#pragma unroll
            for (int ct = 0; ct < 8; ++ct)
                Ob[(size_t)row * 128 + ct * 16 + c] = f2bf(acc[ct][reg]);
            float av = acc[8][reg];
            if (H == 8) {
                if (c < 8) as_out[(size_t)row * 8 + c] = av;
                else       ad_out[(size_t)row * 8 + (c - 8)] = av;
            } else {
                if (c == 0)      as_out[row] = av;
                else if (c == 1) ad_out[row] = av;
            }
        }
    }
}

// ---------------- aggregation: 1 node per 16-lane group, inline weights ----------------
// block 256 = 16 nodes; lane cl owns channels cl*8..cl*8+7. No cross-lane reduce.

template <int H, int OBF>
__global__ __launch_bounds__(256) void agg_kernel(const int* __restrict__ rowptr,
                                                  const int* __restrict__ colsrc,
                                                  const unsigned short* __restrict__ hb,
                                                  const float* __restrict__ as,
                                                  const float* __restrict__ ad,
                                                  const float* __restrict__ bias,
                                                  void* __restrict__ outv, int n) {
    int tid = threadIdx.x;
    int node = blockIdx.x * 16 + (tid >> 4);
    int cl = tid & 15;
    if (node >= n) return;
    int beg = rowptr[node];
    int end = rowptr[node + 1];
    int head = (H == 8) ? (cl >> 1) : 0;
    float adh = ad[(size_t)node * H + head];

    float acc[8];
#pragma unroll
    for (int c = 0; c < 8; ++c) acc[c] = 0.f;
    float den = 0.f;

#pragma unroll 2
    for (int i = beg; i < end; ++i) {
        int s = colsrc[i];
        float ev = as[(size_t)s * H + head] + adh;
        ev = (ev > 0.f) ? ev : NEG_SLOPE * ev;
        float wgt = __expf(ev);
        den += wgt;
        uint4 a = *(const uint4*)(hb + (size_t)s * 128 + cl * 8);
        unsigned int u[4] = {a.x, a.y, a.z, a.w};
#pragma unroll
        for (int k = 0; k < 4; ++k) {
            float lo = __uint_as_float(u[k] << 16);
            float hi = __uint_as_float(u[k] & 0xffff0000u);
            acc[2 * k]     += wgt * lo;
            acc[2 * k + 1] += wgt * hi;
        }
    }

    float inv = 1.0f / den;
    float r[8];
#pragma unroll
    for (int k = 0; k < 8; ++k) {
        r[k] = acc[k] * inv + bias[cl * 8 + k];
        if (OBF) r[k] = (r[k] > 0.f) ? r[k] : expm1f(r[k]);  // ELU (layer 1)
    }
    if (OBF) {
        unsigned short o[8];
#pragma unroll
        for (int k = 0; k < 8; ++k) o[k] = f2bf(r[k]);
        *(uint4*)((unsigned short*)outv + (size_t)node * 128 + cl * 8) = *(uint4*)o;
    } else {
        float4* p = (float4*)((float*)outv + (size_t)node * 128 + cl * 8);
        p[0] = make_float4(r[0], r[1], r[2], r[3]);
        p[1] = make_float4(r[4], r[5], r[6], r[7]);
    }
}

// ---------------- launch ----------------

extern "C" void kernel_launch(void* const* d_in, const int* in_sizes, int n_in,
                              void* d_out, int out_size, void* d_ws, size_t ws_size,
                              hipStream_t stream) {
    const float* x    = (const float*)d_in[0];
    const int*   ei   = (const int*)d_in[1];
    const float* W1   = (const float*)d_in[2];
    const float* a_s1 = (const float*)d_in[3];
    const float* a_d1 = (const float*)d_in[4];
    const float* b1   = (const float*)d_in[5];
    const float* W2   = (const float*)d_in[6];
    const float* a_s2 = (const float*)d_in[7];
    const float* a_d2 = (const float*)d_in[8];
    const float* b2   = (const float*)d_in[9];

    const int n  = in_sizes[0] / 128;
    const int e  = in_sizes[1] / 2;
    const int en = e + n;
    const int nb = (n + 1023) / 1024;

    char* ws = (char*)d_ws;
    size_t off = 0;
    auto alloc = [&](size_t bytes) -> void* {
        void* p = ws + off;
        off += (bytes + 255) & ~(size_t)255;
        return p;
    };
    unsigned short* hb   = (unsigned short*)alloc((size_t)n * 128 * 2);
    unsigned short* hmid = (unsigned short*)alloc((size_t)n * 128 * 2);
    float* as1    = (float*)alloc((size_t)n * 8 * 4);
    float* ad1    = (float*)alloc((size_t)n * 8 * 4);
    float* as2    = (float*)alloc((size_t)n * 4);
    float* ad2    = (float*)alloc((size_t)n * 4);
    int*   cnt    = (int*)alloc((size_t)n * 4);
    int*   rowptr = (int*)alloc((size_t)(n + 1) * 4);
    int*   colsrc = (int*)alloc((size_t)en * 4);
    int*   pos    = (int*)alloc((size_t)en * 4);
    int*   bsum   = (int*)alloc((size_t)nb * 4);
    int*   bbase  = (int*)alloc((size_t)nb * 4);
    unsigned short* Wf1 = (unsigned short*)alloc(4 * 9 * 64 * 8 * 2);
    unsigned short* Wf2 = (unsigned short*)alloc(4 * 9 * 64 * 8 * 2);

    // CSR build (same graph both layers): assign -> scan -> place
    zero_kernel<<<(n + 255) / 256, 256, 0, stream>>>(cnt, n);
    assign_kernel<<<(en + 255) / 256, 256, 0, stream>>>(ei, e, n, cnt, pos);
    scanA_kernel<<<nb, 256, 0, stream>>>(cnt, bsum, n);
    scanB_kernel<<<1, 64, 0, stream>>>(bsum, bbase, rowptr, nb, n);
    scanC_kernel<<<nb, 256, 0, stream>>>(cnt, bbase, rowptr, n);
    place_kernel<<<(en + 255) / 256, 256, 0, stream>>>(ei, pos, rowptr, e, n, colsrc);

    // weight prep (fragment-ordered bf16 [W | W@a])
    prep_w_kernel<<<4, 256, 0, stream>>>(W1, a_s1, a_d1, 8, Wf1);
    prep_w_kernel<<<4, 256, 0, stream>>>(W2, a_s2, a_d2, 1, Wf2);

    int gemm_grid = (n + 63) / 64;
    int node_grid = (n + 15) / 16;

    // layer 1
    gemm_mfma_kernel<8, false><<<gemm_grid, 256, 0, stream>>>(x, Wf1, hb, as1, ad1, n);
    agg_kernel<8, 1><<<node_grid, 256, 0, stream>>>(rowptr, colsrc, hb, as1, ad1, b1, hmid, n);

    // layer 2
    gemm_mfma_kernel<1, true><<<gemm_grid, 256, 0, stream>>>(hmid, Wf2, hb, as2, ad2, n);
    agg_kernel<1, 0><<<node_grid, 256, 0, stream>>>(rowptr, colsrc, hb, as2, ad2, b2, d_out, n);

    (void)n_in; (void)out_size; (void)ws_size;
}

// Round 10
// 164.204 us; speedup vs baseline: 1.2812x; 1.0115x over previous
//
#include <hip/hip_runtime.h>
#include <hip/hip_bf16.h>

#define NEG_SLOPE 0.2f

typedef short s16x8 __attribute__((ext_vector_type(8)));
typedef float f32x4 __attribute__((ext_vector_type(4)));

__device__ __forceinline__ unsigned short f2bf(float f) {
    unsigned int u = __float_as_uint(f);
    u += 0x7FFFu + ((u >> 16) & 1u);   // RNE
    return (unsigned short)(u >> 16);
}

// ---------------- CSR build ----------------

__global__ void zero_kernel(int* __restrict__ p, int count) {
    int i = blockIdx.x * blockDim.x + threadIdx.x;
    if (i < count) p[i] = 0;
}

// pos[i] = arrival order of edge i at its destination; cnt[dst] counts in-degree.
__global__ void assign_kernel(const int* __restrict__ ei, int e, int n,
                              int* __restrict__ cnt, int* __restrict__ pos) {
    int i = blockIdx.x * blockDim.x + threadIdx.x;
    int total = e + n;
    if (i >= total) return;
    int dst = (i < e) ? ei[e + i] : (i - e);
    pos[i] = atomicAdd(&cnt[dst], 1);
}

__global__ __launch_bounds__(256) void scanA_kernel(const int* __restrict__ cnt, int* __restrict__ bsum, int n) {
    int b = blockIdx.x, t = threadIdx.x;
    int base = b * 1024;
    int s = 0;
#pragma unroll
    for (int q = 0; q < 4; ++q) {
        int i = base + t + q * 256;
        if (i < n) s += cnt[i];
    }
    int lane = t & 63, wid = t >> 6;
#pragma unroll
    for (int off = 32; off; off >>= 1) s += __shfl_xor(s, off, 64);
    __shared__ int ws[4];
    if (lane == 0) ws[wid] = s;
    __syncthreads();
    if (t == 0) bsum[b] = ws[0] + ws[1] + ws[2] + ws[3];
}

__global__ __launch_bounds__(64) void scanB_kernel(const int* __restrict__ bsum, int* __restrict__ bbase,
                                                   int* __restrict__ rowptr, int nb, int n) {
    int t = threadIdx.x;
    int carry = 0;
    for (int c = 0; c < nb; c += 64) {
        int i = c + t;
        int v = (i < nb) ? bsum[i] : 0;
        int incl = v;
#pragma unroll
        for (int off = 1; off < 64; off <<= 1) {
            int u = __shfl_up(incl, off, 64);
            if (t >= off) incl += u;
        }
        if (i < nb) bbase[i] = carry + incl - v;
        carry += __shfl(incl, 63, 64);
    }
    if (t == 0) rowptr[n] = carry;
}

__global__ __launch_bounds__(256) void scanC_kernel(const int* __restrict__ cnt, const int* __restrict__ bbase,
                                                    int* __restrict__ rowptr, int n) {
    int b = blockIdx.x, t = threadIdx.x;
    int idx = b * 1024 + t * 4;
    int4 v = make_int4(0, 0, 0, 0);
    if (idx + 3 < n) v = *(const int4*)(cnt + idx);
    else {
        if (idx < n)     v.x = cnt[idx];
        if (idx + 1 < n) v.y = cnt[idx + 1];
        if (idx + 2 < n) v.z = cnt[idx + 2];
        if (idx + 3 < n) v.w = cnt[idx + 3];
    }
    int s0 = v.x, s1 = s0 + v.y, s2 = s1 + v.z, s3 = s2 + v.w;
    int tot = s3;
    int lane = t & 63, wid = t >> 6;
    int incl = tot;
#pragma unroll
    for (int off = 1; off < 64; off <<= 1) {
        int u = __shfl_up(incl, off, 64);
        if (lane >= off) incl += u;
    }
    __shared__ int wtot[4];
    if (lane == 63) wtot[wid] = incl;
    __syncthreads();
    int woff = 0;
    for (int w = 0; w < wid; ++w) woff += wtot[w];
    int ex = incl - tot + woff + bbase[b];
    if (idx < n)     rowptr[idx]     = ex;
    if (idx + 1 < n) rowptr[idx + 1] = ex + s0;
    if (idx + 2 < n) rowptr[idx + 2] = ex + s1;
    if (idx + 3 < n) rowptr[idx + 3] = ex + s2;
}

// place edge i at colsrc[rowptr[dst] + pos[i]] — no atomics, one random 4B write.
__global__ void place_kernel(const int* __restrict__ ei, const int* __restrict__ pos,
                             const int* __restrict__ rowptr, int e, int n,
                             int* __restrict__ colsrc) {
    int i = blockIdx.x * blockDim.x + threadIdx.x;
    int total = e + n;
    if (i >= total) return;
    int src, dst;
    if (i < e) { src = ei[i]; dst = ei[e + i]; }
    else       { src = i - e; dst = i - e; }
    colsrc[rowptr[dst] + pos[i]] = src;
}

// ---------------- prep: fragment-ordered bf16 [W | W@a] ----------------

__global__ __launch_bounds__(256) void prep_w_kernel(const float* __restrict__ W,
                                                     const float* __restrict__ as_v,
                                                     const float* __restrict__ ad_v,
                                                     int H, unsigned short* __restrict__ Wf) {
    int kt = blockIdx.x;   // 0..3
    int t = threadIdx.x;
    for (int task = t; task < 9 * 64; task += 256) {
        int ct = task / 64, l = task & 63;
        int kbase = kt * 32 + (l >> 4) * 8;
        int c = l & 15;
        unsigned short o[8];
        if (ct < 8) {
            int col = ct * 16 + c;
#pragma unroll
            for (int j = 0; j < 8; ++j) o[j] = f2bf(W[(size_t)(kbase + j) * 128 + col]);
        } else {
#pragma unroll
            for (int j = 0; j < 8; ++j) {
                float s = 0.f;
                if (H == 8) {
                    const float* a = (c < 8) ? as_v : ad_v;
                    int hh = c & 7;
                    for (int m = 0; m < 16; ++m)
                        s += W[(size_t)(kbase + j) * 128 + hh * 16 + m] * a[hh * 16 + m];
                } else if (c < 2) {
                    const float* a = (c == 0) ? as_v : ad_v;
                    for (int m = 0; m < 128; ++m)
                        s += W[(size_t)(kbase + j) * 128 + m] * a[m];
                }
                o[j] = f2bf(s);
            }
        }
        *(uint4*)&Wf[(((size_t)kt * 9 + ct) * 64 + l) * 8] = *(uint4*)o;
    }
}

// ---------------- MFMA GEMM: [h | alpha] = X @ [W | Wa] ----------------

template <int H, bool INBF16>
__global__ __launch_bounds__(256) void gemm_mfma_kernel(const void* __restrict__ Xv,
                                                        const unsigned short* __restrict__ Wf,
                                                        unsigned short* __restrict__ Ob,
                                                        float* __restrict__ as_out,
                                                        float* __restrict__ ad_out, int n) {
    __shared__ unsigned short lds[26624];   // 8192 A + 18432 W
    int tid = threadIdx.x;
    int row0 = blockIdx.x * 64;

    {
        const uint4* src = (const uint4*)Wf;
        uint4* dst = (uint4*)&lds[8192];
#pragma unroll
        for (int i = 0; i < 9; ++i) dst[tid + 256 * i] = src[tid + 256 * i];
    }
#pragma unroll
    for (int q = 0; q < 4; ++q) {
        int task = tid + q * 256;
        int r = task >> 4, kc = task & 15;
        int gr = row0 + r;
        uint4 val = make_uint4(0, 0, 0, 0);
        if (gr < n) {
            if (INBF16) {
                val = *(const uint4*)((const unsigned short*)Xv + (size_t)gr * 128 + kc * 8);
            } else {
                const float4* xp = (const float4*)((const float*)Xv + (size_t)gr * 128 + kc * 8);
                float4 x0 = xp[0], x1 = xp[1];
                unsigned short o[8] = {f2bf(x0.x), f2bf(x0.y), f2bf(x0.z), f2bf(x0.w),
                                       f2bf(x1.x), f2bf(x1.y), f2bf(x1.z), f2bf(x1.w)};
                val = *(uint4*)o;
            }
        }
        int w = r >> 4, kt = kc >> 2, lane = ((kc & 3) << 4) + (r & 15);
        *(uint4*)&lds[(size_t)(((w * 4 + kt) * 64) + lane) * 8] = val;
    }
    __syncthreads();

    int w = tid >> 6, l = tid & 63;
    f32x4 acc[9];
#pragma unroll
    for (int ct = 0; ct < 9; ++ct) acc[ct] = (f32x4){0.f, 0.f, 0.f, 0.f};
#pragma unroll
    for (int kt = 0; kt < 4; ++kt) {
        s16x8 a = *(s16x8*)&lds[(size_t)((w * 4 + kt) * 64 + l) * 8];
#pragma unroll
        for (int ct = 0; ct < 9; ++ct) {
            s16x8 b = *(s16x8*)&lds[8192 + (size_t)((kt * 9 + ct) * 64 + l) * 8];
            acc[ct] = __builtin_amdgcn_mfma_f32_16x16x32_bf16(a, b, acc[ct], 0, 0, 0);
        }
    }

    int c = l & 15, rgrp = l >> 4;
    int rowb = row0 + w * 16 + rgrp * 4;
#pragma unroll
    for (int reg = 0; reg < 4; ++reg) {
        int row = rowb + reg;
        if (row < n) {
#pragma unroll
            for (int ct = 0; ct < 8; ++ct)
                Ob[(size_t)row * 128 + ct * 16 + c] = f2bf(acc[ct][reg]);
            float av = acc[8][reg];
            if (H == 8) {
                if (c < 8) as_out[(size_t)row * 8 + c] = av;
                else       ad_out[(size_t)row * 8 + (c - 8)] = av;
            } else {
                if (c == 0)      as_out[row] = av;
                else if (c == 1) ad_out[row] = av;
            }
        }
    }
}

// ---------------- aggregation: 32 lanes/node = 2 edge-slots x 16 channel-lanes ----------------
// block 256 = 8 nodes; lane cl owns channels cl*8..cl*8+7; 1-level reduce across slots.

template <int H, int OBF>
__global__ __launch_bounds__(256) void agg_kernel(const int* __restrict__ rowptr,
                                                  const int* __restrict__ colsrc,
                                                  const unsigned short* __restrict__ hb,
                                                  const float* __restrict__ as,
                                                  const float* __restrict__ ad,
                                                  const float* __restrict__ bias,
                                                  void* __restrict__ outv, int n) {
    int tid = threadIdx.x;
    int node = blockIdx.x * 8 + (tid >> 5);
    int sub = tid & 31;
    int slot = sub >> 4;     // 0..1
    int cl = sub & 15;       // channel group
    if (node >= n) return;
    int beg = rowptr[node];
    int end = rowptr[node + 1];
    int head = (H == 8) ? (cl >> 1) : 0;
    float adh = ad[(size_t)node * H + head];

    float acc[8];
#pragma unroll
    for (int c = 0; c < 8; ++c) acc[c] = 0.f;
    float den = 0.f;

#pragma unroll 2
    for (int i = beg + slot; i < end; i += 2) {
        int s = colsrc[i];
        float ev = as[(size_t)s * H + head] + adh;
        ev = (ev > 0.f) ? ev : NEG_SLOPE * ev;
        float wgt = __expf(ev);
        den += wgt;
        uint4 a = *(const uint4*)(hb + (size_t)s * 128 + cl * 8);
        unsigned int u[4] = {a.x, a.y, a.z, a.w};
#pragma unroll
        for (int k = 0; k < 4; ++k) {
            float lo = __uint_as_float(u[k] << 16);
            float hi = __uint_as_float(u[k] & 0xffff0000u);
            acc[2 * k]     += wgt * lo;
            acc[2 * k + 1] += wgt * hi;
        }
    }

    // 1-level reduce across the 2 slots (stride 16)
    den += __shfl_xor(den, 16, 64);
#pragma unroll
    for (int c = 0; c < 8; ++c) acc[c] += __shfl_xor(acc[c], 16, 64);

    if (slot == 0) {
        float inv = 1.0f / den;
        float r[8];
#pragma unroll
        for (int k = 0; k < 8; ++k) {
            r[k] = acc[k] * inv + bias[cl * 8 + k];
            if (OBF) r[k] = (r[k] > 0.f) ? r[k] : expm1f(r[k]);  // ELU (layer 1)
        }
        if (OBF) {
            unsigned short o[8];
#pragma unroll
            for (int k = 0; k < 8; ++k) o[k] = f2bf(r[k]);
            *(uint4*)((unsigned short*)outv + (size_t)node * 128 + cl * 8) = *(uint4*)o;
        } else {
            float4* p = (float4*)((float*)outv + (size_t)node * 128 + cl * 8);
            p[0] = make_float4(r[0], r[1], r[2], r[3]);
            p[1] = make_float4(r[4], r[5], r[6], r[7]);
        }
    }
}

// ---------------- launch ----------------

extern "C" void kernel_launch(void* const* d_in, const int* in_sizes, int n_in,
                              void* d_out, int out_size, void* d_ws, size_t ws_size,
                              hipStream_t stream) {
    const float* x    = (const float*)d_in[0];
    const int*   ei   = (const int*)d_in[1];
    const float* W1   = (const float*)d_in[2];
    const float* a_s1 = (const float*)d_in[3];
    const float* a_d1 = (const float*)d_in[4];
    const float* b1   = (const float*)d_in[5];
    const float* W2   = (const float*)d_in[6];
    const float* a_s2 = (const float*)d_in[7];
    const float* a_d2 = (const float*)d_in[8];
    const float* b2   = (const float*)d_in[9];

    const int n  = in_sizes[0] / 128;
    const int e  = in_sizes[1] / 2;
    const int en = e + n;
    const int nb = (n + 1023) / 1024;

    char* ws = (char*)d_ws;
    size_t off = 0;
    auto alloc = [&](size_t bytes) -> void* {
        void* p = ws + off;
        off += (bytes + 255) & ~(size_t)255;
        return p;
    };
    unsigned short* hb   = (unsigned short*)alloc((size_t)n * 128 * 2);
    unsigned short* hmid = (unsigned short*)alloc((size_t)n * 128 * 2);
    float* as1    = (float*)alloc((size_t)n * 8 * 4);
    float* ad1    = (float*)alloc((size_t)n * 8 * 4);
    float* as2    = (float*)alloc((size_t)n * 4);
    float* ad2    = (float*)alloc((size_t)n * 4);
    int*   cnt    = (int*)alloc((size_t)n * 4);
    int*   rowptr = (int*)alloc((size_t)(n + 1) * 4);
    int*   colsrc = (int*)alloc((size_t)en * 4);
    int*   pos    = (int*)alloc((size_t)en * 4);
    int*   bsum   = (int*)alloc((size_t)nb * 4);
    int*   bbase  = (int*)alloc((size_t)nb * 4);
    unsigned short* Wf1 = (unsigned short*)alloc(4 * 9 * 64 * 8 * 2);
    unsigned short* Wf2 = (unsigned short*)alloc(4 * 9 * 64 * 8 * 2);

    // CSR build (same graph both layers): assign -> scan -> place
    zero_kernel<<<(n + 255) / 256, 256, 0, stream>>>(cnt, n);
    assign_kernel<<<(en + 255) / 256, 256, 0, stream>>>(ei, e, n, cnt, pos);
    scanA_kernel<<<nb, 256, 0, stream>>>(cnt, bsum, n);
    scanB_kernel<<<1, 64, 0, stream>>>(bsum, bbase, rowptr, nb, n);
    scanC_kernel<<<nb, 256, 0, stream>>>(cnt, bbase, rowptr, n);
    place_kernel<<<(en + 255) / 256, 256, 0, stream>>>(ei, pos, rowptr, e, n, colsrc);

    // weight prep (fragment-ordered bf16 [W | W@a])
    prep_w_kernel<<<4, 256, 0, stream>>>(W1, a_s1, a_d1, 8, Wf1);
    prep_w_kernel<<<4, 256, 0, stream>>>(W2, a_s2, a_d2, 1, Wf2);

    int gemm_grid = (n + 63) / 64;
    int node_grid = (n + 7) / 8;

    // layer 1
    gemm_mfma_kernel<8, false><<<gemm_grid, 256, 0, stream>>>(x, Wf1, hb, as1, ad1, n);
    agg_kernel<8, 1><<<node_grid, 256, 0, stream>>>(rowptr, colsrc, hb, as1, ad1, b1, hmid, n);

    // layer 2
    gemm_mfma_kernel<1, true><<<gemm_grid, 256, 0, stream>>>(hmid, Wf2, hb, as2, ad2, n);
    agg_kernel<1, 0><<<node_grid, 256, 0, stream>>>(rowptr, colsrc, hb, as2, ad2, b2, d_out, n);

    (void)n_in; (void)out_size; (void)ws_size;
}

// Round 11
// 149.365 us; speedup vs baseline: 1.4084x; 1.0994x over previous
//
#include <hip/hip_runtime.h>
#include <hip/hip_bf16.h>

#define NEG_SLOPE 0.2f

typedef short s16x8 __attribute__((ext_vector_type(8)));
typedef float f32x4 __attribute__((ext_vector_type(4)));

__device__ __forceinline__ unsigned short f2bf(float f) {
    unsigned int u = __float_as_uint(f);
    u += 0x7FFFu + ((u >> 16) & 1u);   // RNE
    return (unsigned short)(u >> 16);
}

// ---------------- bucket-partitioned CSR build ----------------
// Buckets of 256 dst nodes (bucket = dst>>8); n < 65536 so (src, dst&255) packs in 4B.

__global__ void zero_kernel(int* __restrict__ p, int count) {
    int i = blockIdx.x * blockDim.x + threadIdx.x;
    if (i < count) p[i] = 0;
}

// P1: global histogram of dst>>8 (LDS-aggregated)
__global__ __launch_bounds__(256) void hist_kernel(const int* __restrict__ ei, int e, int n,
                                                   int* __restrict__ ghist) {
    __shared__ int lh[256];
    int t = threadIdx.x;
    lh[t] = 0;
    __syncthreads();
    int base = blockIdx.x * 2048;
    int en = e + n;
#pragma unroll
    for (int q = 0; q < 8; ++q) {
        int i = base + q * 256 + t;
        if (i < en) {
            int dst = (i < e) ? ei[e + i] : (i - e);
            atomicAdd(&lh[dst >> 8], 1);
        }
    }
    __syncthreads();
    if (lh[t]) atomicAdd(&ghist[t], lh[t]);
}

// P2: exclusive scan of 256 bucket counts -> gbase, gcursor
__global__ __launch_bounds__(256) void bscan_kernel(const int* __restrict__ ghist,
                                                    int* __restrict__ gbase,
                                                    int* __restrict__ gcursor) {
    __shared__ int s[256];
    int t = threadIdx.x;
    int v = ghist[t];
    s[t] = v;
    __syncthreads();
    for (int off = 1; off < 256; off <<= 1) {
        int u = (t >= off) ? s[t - off] : 0;
        __syncthreads();
        s[t] += u;
        __syncthreads();
    }
    int ex = s[t] - v;
    gbase[t] = ex;
    gcursor[t] = ex;
}

// P3: scatter packed edges into bucket regions (per-block LDS ranking)
__global__ __launch_bounds__(256) void scatter_kernel(const int* __restrict__ ei, int e, int n,
                                                      int* __restrict__ gcursor,
                                                      unsigned int* __restrict__ gpair) {
    __shared__ int lh[256], lbase[256];
    int t = threadIdx.x;
    lh[t] = 0;
    __syncthreads();
    int base = blockIdx.x * 2048;
    int en = e + n;
    int bk[8], rk[8];
    unsigned int pk[8];
#pragma unroll
    for (int q = 0; q < 8; ++q) {
        int i = base + q * 256 + t;
        bk[q] = -1;
        if (i < en) {
            int src, dst;
            if (i < e) { src = ei[i]; dst = ei[e + i]; }
            else       { src = i - e; dst = i - e; }
            int b = dst >> 8;
            bk[q] = b;
            rk[q] = atomicAdd(&lh[b], 1);
            pk[q] = (unsigned int)src | ((unsigned int)(dst & 255) << 16);
        }
    }
    __syncthreads();
    if (lh[t]) lbase[t] = atomicAdd(&gcursor[t], lh[t]);
    __syncthreads();
#pragma unroll
    for (int q = 0; q < 8; ++q)
        if (bk[q] >= 0) gpair[lbase[bk[q]] + rk[q]] = pk[q];
}

// P4: per-bucket local CSR (count -> scan -> place), all in LDS / L2-hot window
__global__ __launch_bounds__(256) void bucket_csr_kernel(const unsigned int* __restrict__ gpair,
                                                         const int* __restrict__ gbase,
                                                         int* __restrict__ rowptr,
                                                         int* __restrict__ colsrc, int n, int en) {
    int b = blockIdx.x, t = threadIdx.x;
    __shared__ int cnt[256], scn[256], cur[256];
    cnt[t] = 0;
    __syncthreads();
    int beg = gbase[b];
    int end = (b < 255) ? gbase[b + 1] : en;
    for (int i = beg + t; i < end; i += 256)
        atomicAdd(&cnt[gpair[i] >> 16], 1);
    __syncthreads();
    int v = cnt[t];
    scn[t] = v;
    __syncthreads();
    for (int off = 1; off < 256; off <<= 1) {
        int u = (t >= off) ? scn[t - off] : 0;
        __syncthreads();
        scn[t] += u;
        __syncthreads();
    }
    int ex = scn[t] - v;
    cur[t] = ex;
    int node = b * 256 + t;
    if (node < n) rowptr[node] = beg + ex;
    if (b == 0 && t == 0) rowptr[n] = en;
    __syncthreads();
    for (int i = beg + t; i < end; i += 256) {
        unsigned int p = gpair[i];
        int ofs = atomicAdd(&cur[p >> 16], 1);
        colsrc[beg + ofs] = (int)(p & 0xFFFFu);
    }
}

// ---------------- prep: fragment-ordered bf16 [W | W@a], both layers fused ----------------

__global__ __launch_bounds__(256) void prep_w_kernel(const float* __restrict__ W1,
                                                     const float* __restrict__ as1,
                                                     const float* __restrict__ ad1,
                                                     unsigned short* __restrict__ Wf1,
                                                     const float* __restrict__ W2,
                                                     const float* __restrict__ as2,
                                                     const float* __restrict__ ad2,
                                                     unsigned short* __restrict__ Wf2) {
    int layer = blockIdx.x >> 2;
    int kt = blockIdx.x & 3;
    const float* W = layer ? W2 : W1;
    const float* as_v = layer ? as2 : as1;
    const float* ad_v = layer ? ad2 : ad1;
    unsigned short* Wf = layer ? Wf2 : Wf1;
    int H = layer ? 1 : 8;
    int t = threadIdx.x;
    for (int task = t; task < 9 * 64; task += 256) {
        int ct = task / 64, l = task & 63;
        int kbase = kt * 32 + (l >> 4) * 8;
        int c = l & 15;
        unsigned short o[8];
        if (ct < 8) {
            int col = ct * 16 + c;
#pragma unroll
            for (int j = 0; j < 8; ++j) o[j] = f2bf(W[(size_t)(kbase + j) * 128 + col]);
        } else {
#pragma unroll
            for (int j = 0; j < 8; ++j) {
                float s = 0.f;
                if (H == 8) {
                    const float* a = (c < 8) ? as_v : ad_v;
                    int hh = c & 7;
                    for (int m = 0; m < 16; ++m)
                        s += W[(size_t)(kbase + j) * 128 + hh * 16 + m] * a[hh * 16 + m];
                } else if (c < 2) {
                    const float* a = (c == 0) ? as_v : ad_v;
                    for (int m = 0; m < 128; ++m)
                        s += W[(size_t)(kbase + j) * 128 + m] * a[m];
                }
                o[j] = f2bf(s);
            }
        }
        *(uint4*)&Wf[(((size_t)kt * 9 + ct) * 64 + l) * 8] = *(uint4*)o;
    }
}

// ---------------- MFMA GEMM: [h | alpha] = X @ [W | Wa] ----------------

template <int H, bool INBF16>
__global__ __launch_bounds__(256) void gemm_mfma_kernel(const void* __restrict__ Xv,
                                                        const unsigned short* __restrict__ Wf,
                                                        unsigned short* __restrict__ Ob,
                                                        float* __restrict__ as_out,
                                                        float* __restrict__ ad_out, int n) {
    __shared__ unsigned short lds[26624];   // 8192 A + 18432 W
    int tid = threadIdx.x;
    int row0 = blockIdx.x * 64;

    {
        const uint4* src = (const uint4*)Wf;
        uint4* dst = (uint4*)&lds[8192];
#pragma unroll
        for (int i = 0; i < 9; ++i) dst[tid + 256 * i] = src[tid + 256 * i];
    }
#pragma unroll
    for (int q = 0; q < 4; ++q) {
        int task = tid + q * 256;
        int r = task >> 4, kc = task & 15;
        int gr = row0 + r;
        uint4 val = make_uint4(0, 0, 0, 0);
        if (gr < n) {
            if (INBF16) {
                val = *(const uint4*)((const unsigned short*)Xv + (size_t)gr * 128 + kc * 8);
            } else {
                const float4* xp = (const float4*)((const float*)Xv + (size_t)gr * 128 + kc * 8);
                float4 x0 = xp[0], x1 = xp[1];
                unsigned short o[8] = {f2bf(x0.x), f2bf(x0.y), f2bf(x0.z), f2bf(x0.w),
                                       f2bf(x1.x), f2bf(x1.y), f2bf(x1.z), f2bf(x1.w)};
                val = *(uint4*)o;
            }
        }
        int w = r >> 4, kt = kc >> 2, lane = ((kc & 3) << 4) + (r & 15);
        *(uint4*)&lds[(size_t)(((w * 4 + kt) * 64) + lane) * 8] = val;
    }
    __syncthreads();

    int w = tid >> 6, l = tid & 63;
    f32x4 acc[9];
#pragma unroll
    for (int ct = 0; ct < 9; ++ct) acc[ct] = (f32x4){0.f, 0.f, 0.f, 0.f};
#pragma unroll
    for (int kt = 0; kt < 4; ++kt) {
        s16x8 a = *(s16x8*)&lds[(size_t)((w * 4 + kt) * 64 + l) * 8];
#pragma unroll
        for (int ct = 0; ct < 9; ++ct) {
            s16x8 b = *(s16x8*)&lds[8192 + (size_t)((kt * 9 + ct) * 64 + l) * 8];
            acc[ct] = __builtin_amdgcn_mfma_f32_16x16x32_bf16(a, b, acc[ct], 0, 0, 0);
        }
    }

    int c = l & 15, rgrp = l >> 4;
    int rowb = row0 + w * 16 + rgrp * 4;
#pragma unroll
    for (int reg = 0; reg < 4; ++reg) {
        int row = rowb + reg;
        if (row < n) {
#pragma unroll
            for (int ct = 0; ct < 8; ++ct)
                Ob[(size_t)row * 128 + ct * 16 + c] = f2bf(acc[ct][reg]);
            float av = acc[8][reg];
            if (H == 8) {
                if (c < 8) as_out[(size_t)row * 8 + c] = av;
                else       ad_out[(size_t)row * 8 + (c - 8)] = av;
            } else {
                if (c == 0)      as_out[row] = av;
                else if (c == 1) ad_out[row] = av;
            }
        }
    }
}

// ---------------- aggregation: 32 lanes/node = 2 edge-slots x 16 channel-lanes ----------------

template <int H, int OBF>
__global__ __launch_bounds__(256) void agg_kernel(const int* __restrict__ rowptr,
                                                  const int* __restrict__ colsrc,
                                                  const unsigned short* __restrict__ hb,
                                                  const float* __restrict__ as,
                                                  const float* __restrict__ ad,
                                                  const float* __restrict__ bias,
                                                  void* __restrict__ outv, int n) {
    int tid = threadIdx.x;
    int node = blockIdx.x * 8 + (tid >> 5);
    int sub = tid & 31;
    int slot = sub >> 4;
    int cl = sub & 15;
    if (node >= n) return;
    int beg = rowptr[node];
    int end = rowptr[node + 1];
    int head = (H == 8) ? (cl >> 1) : 0;
    float adh = ad[(size_t)node * H + head];

    float acc[8];
#pragma unroll
    for (int c = 0; c < 8; ++c) acc[c] = 0.f;
    float den = 0.f;

#pragma unroll 2
    for (int i = beg + slot; i < end; i += 2) {
        int s = colsrc[i];
        float ev = as[(size_t)s * H + head] + adh;
        ev = (ev > 0.f) ? ev : NEG_SLOPE * ev;
        float wgt = __expf(ev);
        den += wgt;
        uint4 a = *(const uint4*)(hb + (size_t)s * 128 + cl * 8);
        unsigned int u[4] = {a.x, a.y, a.z, a.w};
#pragma unroll
        for (int k = 0; k < 4; ++k) {
            float lo = __uint_as_float(u[k] << 16);
            float hi = __uint_as_float(u[k] & 0xffff0000u);
            acc[2 * k]     += wgt * lo;
            acc[2 * k + 1] += wgt * hi;
        }
    }

    den += __shfl_xor(den, 16, 64);
#pragma unroll
    for (int c = 0; c < 8; ++c) acc[c] += __shfl_xor(acc[c], 16, 64);

    if (slot == 0) {
        float inv = 1.0f / den;
        float r[8];
#pragma unroll
        for (int k = 0; k < 8; ++k) {
            r[k] = acc[k] * inv + bias[cl * 8 + k];
            if (OBF) r[k] = (r[k] > 0.f) ? r[k] : expm1f(r[k]);  // ELU (layer 1)
        }
        if (OBF) {
            unsigned short o[8];
#pragma unroll
            for (int k = 0; k < 8; ++k) o[k] = f2bf(r[k]);
            *(uint4*)((unsigned short*)outv + (size_t)node * 128 + cl * 8) = *(uint4*)o;
        } else {
            float4* p = (float4*)((float*)outv + (size_t)node * 128 + cl * 8);
            p[0] = make_float4(r[0], r[1], r[2], r[3]);
            p[1] = make_float4(r[4], r[5], r[6], r[7]);
        }
    }
}

// ---------------- launch ----------------

extern "C" void kernel_launch(void* const* d_in, const int* in_sizes, int n_in,
                              void* d_out, int out_size, void* d_ws, size_t ws_size,
                              hipStream_t stream) {
    const float* x    = (const float*)d_in[0];
    const int*   ei   = (const int*)d_in[1];
    const float* W1   = (const float*)d_in[2];
    const float* a_s1 = (const float*)d_in[3];
    const float* a_d1 = (const float*)d_in[4];
    const float* b1   = (const float*)d_in[5];
    const float* W2   = (const float*)d_in[6];
    const float* a_s2 = (const float*)d_in[7];
    const float* a_d2 = (const float*)d_in[8];
    const float* b2   = (const float*)d_in[9];

    const int n  = in_sizes[0] / 128;
    const int e  = in_sizes[1] / 2;
    const int en = e + n;
    const int nbuck = (n + 255) >> 8;           // 196 for n=50000 (n<65536 assumed for packing)
    const int echunks = (en + 2047) / 2048;

    char* ws = (char*)d_ws;
    size_t off = 0;
    auto alloc = [&](size_t bytes) -> void* {
        void* p = ws + off;
        off += (bytes + 255) & ~(size_t)255;
        return p;
    };
    unsigned short* hb   = (unsigned short*)alloc((size_t)n * 128 * 2);
    unsigned short* hmid = (unsigned short*)alloc((size_t)n * 128 * 2);
    float* as1    = (float*)alloc((size_t)n * 8 * 4);
    float* ad1    = (float*)alloc((size_t)n * 8 * 4);
    float* as2    = (float*)alloc((size_t)n * 4);
    float* ad2    = (float*)alloc((size_t)n * 4);
    int*   rowptr = (int*)alloc((size_t)(n + 1) * 4);
    int*   colsrc = (int*)alloc((size_t)en * 4);
    unsigned int* gpair = (unsigned int*)alloc((size_t)en * 4);
    int*   ghist  = (int*)alloc(256 * 4);
    int*   gbase  = (int*)alloc(256 * 4);
    int*   gcursor= (int*)alloc(256 * 4);
    unsigned short* Wf1 = (unsigned short*)alloc(4 * 9 * 64 * 8 * 2);
    unsigned short* Wf2 = (unsigned short*)alloc(4 * 9 * 64 * 8 * 2);

    // CSR build via 256-node bucket partition (same graph both layers)
    zero_kernel<<<1, 256, 0, stream>>>(ghist, 256);
    hist_kernel<<<echunks, 256, 0, stream>>>(ei, e, n, ghist);
    bscan_kernel<<<1, 256, 0, stream>>>(ghist, gbase, gcursor);
    scatter_kernel<<<echunks, 256, 0, stream>>>(ei, e, n, gcursor, gpair);
    bucket_csr_kernel<<<nbuck, 256, 0, stream>>>(gpair, gbase, rowptr, colsrc, n, en);

    // weight prep, both layers in one launch
    prep_w_kernel<<<8, 256, 0, stream>>>(W1, a_s1, a_d1, Wf1, W2, a_s2, a_d2, Wf2);

    int gemm_grid = (n + 63) / 64;
    int node_grid = (n + 7) / 8;

    // layer 1
    gemm_mfma_kernel<8, false><<<gemm_grid, 256, 0, stream>>>(x, Wf1, hb, as1, ad1, n);
    agg_kernel<8, 1><<<node_grid, 256, 0, stream>>>(rowptr, colsrc, hb, as1, ad1, b1, hmid, n);

    // layer 2
    gemm_mfma_kernel<1, true><<<gemm_grid, 256, 0, stream>>>(hmid, Wf2, hb, as2, ad2, n);
    agg_kernel<1, 0><<<node_grid, 256, 0, stream>>>(rowptr, colsrc, hb, as2, ad2, b2, d_out, n);

    (void)n_in; (void)out_size; (void)ws_size;
}

// Round 12
// 133.647 us; speedup vs baseline: 1.5741x; 1.1176x over previous
//
#include <hip/hip_runtime.h>
#include <hip/hip_bf16.h>

#define NEG_SLOPE 0.2f
#define BCAP 8192   // edges per 256-node bucket region (mean 3328, sigma ~58 -> no overflow)

typedef short s16x8 __attribute__((ext_vector_type(8)));
typedef float f32x4 __attribute__((ext_vector_type(4)));

__device__ __forceinline__ unsigned short f2bf(float f) {
    unsigned int u = __float_as_uint(f);
    u += 0x7FFFu + ((u >> 16) & 1u);   // RNE
    return (unsigned short)(u >> 16);
}

// ---------------- prep: fragment-ordered bf16 [W | W@a] + cursor zero ----------------
// blocks 0-7: weight prep (layer = bid>>2, kt = bid&3). block 8: zero gcursor, rowptr[n].

__global__ __launch_bounds__(256) void prep_w_kernel(const float* __restrict__ W1,
                                                     const float* __restrict__ as1,
                                                     const float* __restrict__ ad1,
                                                     unsigned short* __restrict__ Wf1,
                                                     const float* __restrict__ W2,
                                                     const float* __restrict__ as2,
                                                     const float* __restrict__ ad2,
                                                     unsigned short* __restrict__ Wf2,
                                                     int* __restrict__ gcursor,
                                                     int* __restrict__ rowptr, int n, int en) {
    int bid = blockIdx.x;
    int t = threadIdx.x;
    if (bid == 8) {
        gcursor[t] = 0;
        if (t == 0) rowptr[n] = en;
        return;
    }
    int layer = bid >> 2;
    int kt = bid & 3;
    const float* W = layer ? W2 : W1;
    const float* as_v = layer ? as2 : as1;
    const float* ad_v = layer ? ad2 : ad1;
    unsigned short* Wf = layer ? Wf2 : Wf1;
    int H = layer ? 1 : 8;
    for (int task = t; task < 9 * 64; task += 256) {
        int ct = task / 64, l = task & 63;
        int kbase = kt * 32 + (l >> 4) * 8;
        int c = l & 15;
        unsigned short o[8];
        if (ct < 8) {
            int col = ct * 16 + c;
#pragma unroll
            for (int j = 0; j < 8; ++j) o[j] = f2bf(W[(size_t)(kbase + j) * 128 + col]);
        } else {
#pragma unroll
            for (int j = 0; j < 8; ++j) {
                float s = 0.f;
                if (H == 8) {
                    const float* a = (c < 8) ? as_v : ad_v;
                    int hh = c & 7;
                    for (int m = 0; m < 16; ++m)
                        s += W[(size_t)(kbase + j) * 128 + hh * 16 + m] * a[hh * 16 + m];
                } else if (c < 2) {
                    const float* a = (c == 0) ? as_v : ad_v;
                    for (int m = 0; m < 128; ++m)
                        s += W[(size_t)(kbase + j) * 128 + m] * a[m];
                }
                o[j] = f2bf(s);
            }
        }
        *(uint4*)&Wf[(((size_t)kt * 9 + ct) * 64 + l) * 8] = *(uint4*)o;
    }
}

// ---------------- CSR: scatter into fixed-capacity bucket bins ----------------

__global__ __launch_bounds__(256) void scatter_kernel(const int* __restrict__ ei, int e, int n,
                                                      int* __restrict__ gcursor,
                                                      unsigned int* __restrict__ gpair) {
    __shared__ int lh[256], lbase[256];
    int t = threadIdx.x;
    lh[t] = 0;
    __syncthreads();
    int base = blockIdx.x * 2048;
    int en = e + n;
    int bk[8], rk[8];
    unsigned int pk[8];
#pragma unroll
    for (int q = 0; q < 8; ++q) {
        int i = base + q * 256 + t;
        bk[q] = -1;
        if (i < en) {
            int src, dst;
            if (i < e) { src = ei[i]; dst = ei[e + i]; }
            else       { src = i - e; dst = i - e; }
            int b = dst >> 8;
            bk[q] = b;
            rk[q] = atomicAdd(&lh[b], 1);
            pk[q] = (unsigned int)src | ((unsigned int)(dst & 255) << 16);
        }
    }
    __syncthreads();
    if (lh[t]) lbase[t] = atomicAdd(&gcursor[t], lh[t]);
    __syncthreads();
#pragma unroll
    for (int q = 0; q < 8; ++q)
        if (bk[q] >= 0) gpair[(size_t)bk[q] * BCAP + lbase[bk[q]] + rk[q]] = pk[q];
}

// ---------------- CSR: per-bucket local build (count -> scan -> place) ----------------

__global__ __launch_bounds__(256) void bucket_csr_kernel(const unsigned int* __restrict__ gpair,
                                                         const int* __restrict__ gcursor,
                                                         int* __restrict__ rowptr,
                                                         int* __restrict__ colsrc, int n) {
    int b = blockIdx.x, t = threadIdx.x;
    __shared__ int bscan[256], cnt[256], scn[256], cur[256];
    // global edge base = exclusive sum of bucket counts
    int bc = gcursor[t];
    bscan[t] = bc;
    cnt[t] = 0;
    __syncthreads();
    for (int off = 1; off < 256; off <<= 1) {
        int u = (t >= off) ? bscan[t - off] : 0;
        __syncthreads();
        bscan[t] += u;
        __syncthreads();
    }
    int mybase = bscan[b] - gcursor[b];   // exclusive
    int mycnt = gcursor[b];
    const unsigned int* mypair = gpair + (size_t)b * BCAP;
    for (int i = t; i < mycnt; i += 256)
        atomicAdd(&cnt[mypair[i] >> 16], 1);
    __syncthreads();
    int v = cnt[t];
    scn[t] = v;
    __syncthreads();
    for (int off = 1; off < 256; off <<= 1) {
        int u = (t >= off) ? scn[t - off] : 0;
        __syncthreads();
        scn[t] += u;
        __syncthreads();
    }
    int ex = scn[t] - v;
    cur[t] = ex;
    int node = b * 256 + t;
    if (node < n) rowptr[node] = mybase + ex;
    __syncthreads();
    for (int i = t; i < mycnt; i += 256) {
        unsigned int p = mypair[i];
        int ofs = atomicAdd(&cur[p >> 16], 1);
        colsrc[mybase + ofs] = (int)(p & 0xFFFFu);
    }
}

// ---------------- MFMA GEMM: [h | alpha] = X @ [W | Wa]; B frags direct from global ----------------

template <int H, bool INBF16>
__global__ __launch_bounds__(256) void gemm_mfma_kernel(const void* __restrict__ Xv,
                                                        const unsigned short* __restrict__ Wf,
                                                        unsigned short* __restrict__ Ob,
                                                        float* __restrict__ as_out,
                                                        float* __restrict__ ad_out, int n) {
    __shared__ unsigned short lds[8192];   // A frags only (16 KB)
    int tid = threadIdx.x;
    int row0 = blockIdx.x * 64;

    // stage A frags
#pragma unroll
    for (int q = 0; q < 4; ++q) {
        int task = tid + q * 256;
        int r = task >> 4, kc = task & 15;
        int gr = row0 + r;
        uint4 val = make_uint4(0, 0, 0, 0);
        if (gr < n) {
            if (INBF16) {
                val = *(const uint4*)((const unsigned short*)Xv + (size_t)gr * 128 + kc * 8);
            } else {
                const float4* xp = (const float4*)((const float*)Xv + (size_t)gr * 128 + kc * 8);
                float4 x0 = xp[0], x1 = xp[1];
                unsigned short o[8] = {f2bf(x0.x), f2bf(x0.y), f2bf(x0.z), f2bf(x0.w),
                                       f2bf(x1.x), f2bf(x1.y), f2bf(x1.z), f2bf(x1.w)};
                val = *(uint4*)o;
            }
        }
        int w = r >> 4, kt = kc >> 2, lane = ((kc & 3) << 4) + (r & 15);
        *(uint4*)&lds[(size_t)(((w * 4 + kt) * 64) + lane) * 8] = val;
    }
    __syncthreads();

    int w = tid >> 6, l = tid & 63;
    // A frags to registers (4 kt x 16B)
    s16x8 a[4];
#pragma unroll
    for (int kt = 0; kt < 4; ++kt)
        a[kt] = *(s16x8*)&lds[(size_t)((w * 4 + kt) * 64 + l) * 8];

    const s16x8* bp = (const s16x8*)Wf;   // [(kt*9+ct)*64 + l]
    f32x4 acc[9];
#pragma unroll
    for (int ct = 0; ct < 9; ++ct) acc[ct] = (f32x4){0.f, 0.f, 0.f, 0.f};
#pragma unroll
    for (int ct = 0; ct < 9; ++ct) {
#pragma unroll
        for (int kt = 0; kt < 4; ++kt) {
            s16x8 b = bp[(kt * 9 + ct) * 64 + l];
            acc[ct] = __builtin_amdgcn_mfma_f32_16x16x32_bf16(a[kt], b, acc[ct], 0, 0, 0);
        }
    }

    int c = l & 15, rgrp = l >> 4;
    int rowb = row0 + w * 16 + rgrp * 4;
#pragma unroll
    for (int reg = 0; reg < 4; ++reg) {
        int row = rowb + reg;
        if (row < n) {
#pragma unroll
            for (int ct = 0; ct < 8; ++ct)
                Ob[(size_t)row * 128 + ct * 16 + c] = f2bf(acc[ct][reg]);
            float av = acc[8][reg];
            if (H == 8) {
                if (c < 8) as_out[(size_t)row * 8 + c] = av;
                else       ad_out[(size_t)row * 8 + (c - 8)] = av;
            } else {
                if (c == 0)      as_out[row] = av;
                else if (c == 1) ad_out[row] = av;
            }
        }
    }
}

// ---------------- aggregation: 32 lanes/node = 2 edge-slots x 16 channel-lanes ----------------

template <int H, int OBF>
__global__ __launch_bounds__(256) void agg_kernel(const int* __restrict__ rowptr,
                                                  const int* __restrict__ colsrc,
                                                  const unsigned short* __restrict__ hb,
                                                  const float* __restrict__ as,
                                                  const float* __restrict__ ad,
                                                  const float* __restrict__ bias,
                                                  void* __restrict__ outv, int n) {
    int tid = threadIdx.x;
    int node = blockIdx.x * 8 + (tid >> 5);
    int sub = tid & 31;
    int slot = sub >> 4;
    int cl = sub & 15;
    if (node >= n) return;
    int beg = rowptr[node];
    int end = rowptr[node + 1];
    int head = (H == 8) ? (cl >> 1) : 0;
    float adh = ad[(size_t)node * H + head];

    float acc[8];
#pragma unroll
    for (int c = 0; c < 8; ++c) acc[c] = 0.f;
    float den = 0.f;

#pragma unroll 2
    for (int i = beg + slot; i < end; i += 2) {
        int s = colsrc[i];
        float ev = as[(size_t)s * H + head] + adh;
        ev = (ev > 0.f) ? ev : NEG_SLOPE * ev;
        float wgt = __expf(ev);
        den += wgt;
        uint4 a = *(const uint4*)(hb + (size_t)s * 128 + cl * 8);
        unsigned int u[4] = {a.x, a.y, a.z, a.w};
#pragma unroll
        for (int k = 0; k < 4; ++k) {
            float lo = __uint_as_float(u[k] << 16);
            float hi = __uint_as_float(u[k] & 0xffff0000u);
            acc[2 * k]     += wgt * lo;
            acc[2 * k + 1] += wgt * hi;
        }
    }

    den += __shfl_xor(den, 16, 64);
#pragma unroll
    for (int c = 0; c < 8; ++c) acc[c] += __shfl_xor(acc[c], 16, 64);

    if (slot == 0) {
        float inv = 1.0f / den;
        float r[8];
#pragma unroll
        for (int k = 0; k < 8; ++k) {
            r[k] = acc[k] * inv + bias[cl * 8 + k];
            if (OBF) r[k] = (r[k] > 0.f) ? r[k] : expm1f(r[k]);  // ELU (layer 1)
        }
        if (OBF) {
            unsigned short o[8];
#pragma unroll
            for (int k = 0; k < 8; ++k) o[k] = f2bf(r[k]);
            *(uint4*)((unsigned short*)outv + (size_t)node * 128 + cl * 8) = *(uint4*)o;
        } else {
            float4* p = (float4*)((float*)outv + (size_t)node * 128 + cl * 8);
            p[0] = make_float4(r[0], r[1], r[2], r[3]);
            p[1] = make_float4(r[4], r[5], r[6], r[7]);
        }
    }
}

// ---------------- launch ----------------

extern "C" void kernel_launch(void* const* d_in, const int* in_sizes, int n_in,
                              void* d_out, int out_size, void* d_ws, size_t ws_size,
                              hipStream_t stream) {
    const float* x    = (const float*)d_in[0];
    const int*   ei   = (const int*)d_in[1];
    const float* W1   = (const float*)d_in[2];
    const float* a_s1 = (const float*)d_in[3];
    const float* a_d1 = (const float*)d_in[4];
    const float* b1   = (const float*)d_in[5];
    const float* W2   = (const float*)d_in[6];
    const float* a_s2 = (const float*)d_in[7];
    const float* a_d2 = (const float*)d_in[8];
    const float* b2   = (const float*)d_in[9];

    const int n  = in_sizes[0] / 128;
    const int e  = in_sizes[1] / 2;
    const int en = e + n;
    const int nbuck = (n + 255) >> 8;           // 196 for n=50000 (n<65536 for 4B packing)
    const int echunks = (en + 2047) / 2048;

    char* ws = (char*)d_ws;
    size_t off = 0;
    auto alloc = [&](size_t bytes) -> void* {
        void* p = ws + off;
        off += (bytes + 255) & ~(size_t)255;
        return p;
    };
    unsigned short* hb   = (unsigned short*)alloc((size_t)n * 128 * 2);
    unsigned short* hmid = (unsigned short*)alloc((size_t)n * 128 * 2);
    float* as1    = (float*)alloc((size_t)n * 8 * 4);
    float* ad1    = (float*)alloc((size_t)n * 8 * 4);
    float* as2    = (float*)alloc((size_t)n * 4);
    float* ad2    = (float*)alloc((size_t)n * 4);
    int*   rowptr = (int*)alloc((size_t)(n + 1) * 4);
    int*   colsrc = (int*)alloc((size_t)en * 4);
    unsigned int* gpair = (unsigned int*)alloc((size_t)nbuck * BCAP * 4);
    int*   gcursor= (int*)alloc(256 * 4);
    unsigned short* Wf1 = (unsigned short*)alloc(4 * 9 * 64 * 8 * 2);
    unsigned short* Wf2 = (unsigned short*)alloc(4 * 9 * 64 * 8 * 2);

    // prep weights + zero cursors + rowptr[n] (one launch)
    prep_w_kernel<<<9, 256, 0, stream>>>(W1, a_s1, a_d1, Wf1, W2, a_s2, a_d2, Wf2,
                                         gcursor, rowptr, n, en);
    // CSR build: scatter into bins, then per-bucket local CSR
    scatter_kernel<<<echunks, 256, 0, stream>>>(ei, e, n, gcursor, gpair);
    bucket_csr_kernel<<<nbuck, 256, 0, stream>>>(gpair, gcursor, rowptr, colsrc, n);

    int gemm_grid = (n + 63) / 64;
    int node_grid = (n + 7) / 8;

    // layer 1
    gemm_mfma_kernel<8, false><<<gemm_grid, 256, 0, stream>>>(x, Wf1, hb, as1, ad1, n);
    agg_kernel<8, 1><<<node_grid, 256, 0, stream>>>(rowptr, colsrc, hb, as1, ad1, b1, hmid, n);

    // layer 2
    gemm_mfma_kernel<1, true><<<gemm_grid, 256, 0, stream>>>(hmid, Wf2, hb, as2, ad2, n);
    agg_kernel<1, 0><<<node_grid, 256, 0, stream>>>(rowptr, colsrc, hb, as2, ad2, b2, d_out, n);

    (void)n_in; (void)out_size; (void)ws_size;
}

// Round 13
// 131.984 us; speedup vs baseline: 1.5939x; 1.0126x over previous
//
#include <hip/hip_runtime.h>
#include <hip/hip_bf16.h>

#define NEG_SLOPE 0.2f
#define BCAP 8192   // edges per 256-node bucket region (mean 3328, sigma ~58 -> no overflow)

typedef short s16x8 __attribute__((ext_vector_type(8)));
typedef float f32x4 __attribute__((ext_vector_type(4)));

__device__ __forceinline__ unsigned short f2bf(float f) {
    unsigned int u = __float_as_uint(f);
    u += 0x7FFFu + ((u >> 16) & 1u);   // RNE
    return (unsigned short)(u >> 16);
}

// ---------------- prep: fragment-ordered bf16 [W | W@a] + cursor zero ----------------

__global__ __launch_bounds__(256) void prep_w_kernel(const float* __restrict__ W1,
                                                     const float* __restrict__ as1,
                                                     const float* __restrict__ ad1,
                                                     unsigned short* __restrict__ Wf1,
                                                     const float* __restrict__ W2,
                                                     const float* __restrict__ as2,
                                                     const float* __restrict__ ad2,
                                                     unsigned short* __restrict__ Wf2,
                                                     int* __restrict__ gcursor,
                                                     int* __restrict__ rowptr, int n, int en) {
    int bid = blockIdx.x;
    int t = threadIdx.x;
    if (bid == 8) {
        gcursor[t] = 0;
        if (t == 0) rowptr[n] = en;
        return;
    }
    int layer = bid >> 2;
    int kt = bid & 3;
    const float* W = layer ? W2 : W1;
    const float* as_v = layer ? as2 : as1;
    const float* ad_v = layer ? ad2 : ad1;
    unsigned short* Wf = layer ? Wf2 : Wf1;
    int H = layer ? 1 : 8;
    for (int task = t; task < 9 * 64; task += 256) {
        int ct = task / 64, l = task & 63;
        int kbase = kt * 32 + (l >> 4) * 8;
        int c = l & 15;
        unsigned short o[8];
        if (ct < 8) {
            int col = ct * 16 + c;
#pragma unroll
            for (int j = 0; j < 8; ++j) o[j] = f2bf(W[(size_t)(kbase + j) * 128 + col]);
        } else {
#pragma unroll
            for (int j = 0; j < 8; ++j) {
                float s = 0.f;
                if (H == 8) {
                    const float* a = (c < 8) ? as_v : ad_v;
                    int hh = c & 7;
                    for (int m = 0; m < 16; ++m)
                        s += W[(size_t)(kbase + j) * 128 + hh * 16 + m] * a[hh * 16 + m];
                } else if (c < 2) {
                    const float* a = (c == 0) ? as_v : ad_v;
                    for (int m = 0; m < 128; ++m)
                        s += W[(size_t)(kbase + j) * 128 + m] * a[m];
                }
                o[j] = f2bf(s);
            }
        }
        *(uint4*)&Wf[(((size_t)kt * 9 + ct) * 64 + l) * 8] = *(uint4*)o;
    }
}

// ---------------- CSR: scatter into fixed-capacity bucket bins ----------------

__global__ __launch_bounds__(256) void scatter_kernel(const int* __restrict__ ei, int e, int n,
                                                      int* __restrict__ gcursor,
                                                      unsigned int* __restrict__ gpair) {
    __shared__ int lh[256], lbase[256];
    int t = threadIdx.x;
    lh[t] = 0;
    __syncthreads();
    int base = blockIdx.x * 2048;
    int en = e + n;
    int bk[8], rk[8];
    unsigned int pk[8];
#pragma unroll
    for (int q = 0; q < 8; ++q) {
        int i = base + q * 256 + t;
        bk[q] = -1;
        if (i < en) {
            int src, dst;
            if (i < e) { src = ei[i]; dst = ei[e + i]; }
            else       { src = i - e; dst = i - e; }
            int b = dst >> 8;
            bk[q] = b;
            rk[q] = atomicAdd(&lh[b], 1);
            pk[q] = (unsigned int)src | ((unsigned int)(dst & 255) << 16);
        }
    }
    __syncthreads();
    if (lh[t]) lbase[t] = atomicAdd(&gcursor[t], lh[t]);
    __syncthreads();
#pragma unroll
    for (int q = 0; q < 8; ++q)
        if (bk[q] >= 0) gpair[(size_t)bk[q] * BCAP + lbase[bk[q]] + rk[q]] = pk[q];
}

// ---------------- CSR: per-bucket local build (count -> scan -> place) ----------------

__global__ __launch_bounds__(256) void bucket_csr_kernel(const unsigned int* __restrict__ gpair,
                                                         const int* __restrict__ gcursor,
                                                         int* __restrict__ rowptr,
                                                         int* __restrict__ colsrc, int n) {
    int b = blockIdx.x, t = threadIdx.x;
    __shared__ int bscan[256], cnt[256], scn[256], cur[256];
    int bc = gcursor[t];
    bscan[t] = bc;
    cnt[t] = 0;
    __syncthreads();
    for (int off = 1; off < 256; off <<= 1) {
        int u = (t >= off) ? bscan[t - off] : 0;
        __syncthreads();
        bscan[t] += u;
        __syncthreads();
    }
    int mybase = bscan[b] - gcursor[b];   // exclusive
    int mycnt = gcursor[b];
    const unsigned int* mypair = gpair + (size_t)b * BCAP;
    for (int i = t; i < mycnt; i += 256)
        atomicAdd(&cnt[mypair[i] >> 16], 1);
    __syncthreads();
    int v = cnt[t];
    scn[t] = v;
    __syncthreads();
    for (int off = 1; off < 256; off <<= 1) {
        int u = (t >= off) ? scn[t - off] : 0;
        __syncthreads();
        scn[t] += u;
        __syncthreads();
    }
    int ex = scn[t] - v;
    cur[t] = ex;
    int node = b * 256 + t;
    if (node < n) rowptr[node] = mybase + ex;
    __syncthreads();
    for (int i = t; i < mycnt; i += 256) {
        unsigned int p = mypair[i];
        int ofs = atomicAdd(&cur[p >> 16], 1);
        colsrc[mybase + ofs] = (int)(p & 0xFFFFu);
    }
}

// ---------------- MFMA GEMM: [h | alpha] = X @ [W | Wa]; B frags direct from global ----------------

template <int H, bool INBF16>
__global__ __launch_bounds__(256) void gemm_mfma_kernel(const void* __restrict__ Xv,
                                                        const unsigned short* __restrict__ Wf,
                                                        unsigned short* __restrict__ Ob,
                                                        float* __restrict__ as_out,
                                                        float* __restrict__ ad_out, int n) {
    __shared__ unsigned short lds[8192];   // A frags only (16 KB)
    int tid = threadIdx.x;
    int row0 = blockIdx.x * 64;

#pragma unroll
    for (int q = 0; q < 4; ++q) {
        int task = tid + q * 256;
        int r = task >> 4, kc = task & 15;
        int gr = row0 + r;
        uint4 val = make_uint4(0, 0, 0, 0);
        if (gr < n) {
            if (INBF16) {
                val = *(const uint4*)((const unsigned short*)Xv + (size_t)gr * 128 + kc * 8);
            } else {
                const float4* xp = (const float4*)((const float*)Xv + (size_t)gr * 128 + kc * 8);
                float4 x0 = xp[0], x1 = xp[1];
                unsigned short o[8] = {f2bf(x0.x), f2bf(x0.y), f2bf(x0.z), f2bf(x0.w),
                                       f2bf(x1.x), f2bf(x1.y), f2bf(x1.z), f2bf(x1.w)};
                val = *(uint4*)o;
            }
        }
        int w = r >> 4, kt = kc >> 2, lane = ((kc & 3) << 4) + (r & 15);
        *(uint4*)&lds[(size_t)(((w * 4 + kt) * 64) + lane) * 8] = val;
    }
    __syncthreads();

    int w = tid >> 6, l = tid & 63;
    s16x8 a[4];
#pragma unroll
    for (int kt = 0; kt < 4; ++kt)
        a[kt] = *(s16x8*)&lds[(size_t)((w * 4 + kt) * 64 + l) * 8];

    const s16x8* bp = (const s16x8*)Wf;   // [(kt*9+ct)*64 + l]
    f32x4 acc[9];
#pragma unroll
    for (int ct = 0; ct < 9; ++ct) acc[ct] = (f32x4){0.f, 0.f, 0.f, 0.f};
#pragma unroll
    for (int ct = 0; ct < 9; ++ct) {
#pragma unroll
        for (int kt = 0; kt < 4; ++kt) {
            s16x8 b = bp[(kt * 9 + ct) * 64 + l];
            acc[ct] = __builtin_amdgcn_mfma_f32_16x16x32_bf16(a[kt], b, acc[ct], 0, 0, 0);
        }
    }

    int c = l & 15, rgrp = l >> 4;
    int rowb = row0 + w * 16 + rgrp * 4;
#pragma unroll
    for (int reg = 0; reg < 4; ++reg) {
        int row = rowb + reg;
        if (row < n) {
#pragma unroll
            for (int ct = 0; ct < 8; ++ct)
                Ob[(size_t)row * 128 + ct * 16 + c] = f2bf(acc[ct][reg]);
            float av = acc[8][reg];
            if (H == 8) {
                if (c < 8) as_out[(size_t)row * 8 + c] = av;
                else       ad_out[(size_t)row * 8 + (c - 8)] = av;
            } else {
                if (c == 0)      as_out[row] = av;
                else if (c == 1) ad_out[row] = av;
            }
        }
    }
}

// ---------------- aggregation: 16 lanes/node, 4-edge explicit batch, no reduce ----------------
// block 256 = 16 nodes; lane cl owns channels cl*8..cl*8+7; den redundant per lane.

template <int H, int OBF>
__global__ __launch_bounds__(256) void agg_kernel(const int* __restrict__ rowptr,
                                                  const int* __restrict__ colsrc,
                                                  const unsigned short* __restrict__ hb,
                                                  const float* __restrict__ as,
                                                  const float* __restrict__ ad,
                                                  const float* __restrict__ bias,
                                                  void* __restrict__ outv, int n) {
    int tid = threadIdx.x;
    int node = blockIdx.x * 16 + (tid >> 4);
    int cl = tid & 15;
    if (node >= n) return;
    int beg = rowptr[node];
    int end = rowptr[node + 1];
    int head = (H == 8) ? (cl >> 1) : 0;
    float adh = ad[(size_t)node * H + head];

    float acc[8];
#pragma unroll
    for (int c = 0; c < 8; ++c) acc[c] = 0.f;
    float den = 0.f;

    int i = beg;
    // 4-edge batches: 4 index loads, then 4 as-gathers + 4 h-gathers in flight
    for (; i + 4 <= end; i += 4) {
        int s0 = colsrc[i], s1 = colsrc[i + 1], s2 = colsrc[i + 2], s3 = colsrc[i + 3];
        float e0 = as[(size_t)s0 * H + head];
        float e1 = as[(size_t)s1 * H + head];
        float e2 = as[(size_t)s2 * H + head];
        float e3 = as[(size_t)s3 * H + head];
        uint4 a0 = *(const uint4*)(hb + (size_t)s0 * 128 + cl * 8);
        uint4 a1 = *(const uint4*)(hb + (size_t)s1 * 128 + cl * 8);
        uint4 a2 = *(const uint4*)(hb + (size_t)s2 * 128 + cl * 8);
        uint4 a3 = *(const uint4*)(hb + (size_t)s3 * 128 + cl * 8);
        float ev, w0, w1, w2, w3;
        ev = e0 + adh; ev = (ev > 0.f) ? ev : NEG_SLOPE * ev; w0 = __expf(ev);
        ev = e1 + adh; ev = (ev > 0.f) ? ev : NEG_SLOPE * ev; w1 = __expf(ev);
        ev = e2 + adh; ev = (ev > 0.f) ? ev : NEG_SLOPE * ev; w2 = __expf(ev);
        ev = e3 + adh; ev = (ev > 0.f) ? ev : NEG_SLOPE * ev; w3 = __expf(ev);
        den += (w0 + w1) + (w2 + w3);
        unsigned int u0[4] = {a0.x, a0.y, a0.z, a0.w};
        unsigned int u1[4] = {a1.x, a1.y, a1.z, a1.w};
        unsigned int u2[4] = {a2.x, a2.y, a2.z, a2.w};
        unsigned int u3[4] = {a3.x, a3.y, a3.z, a3.w};
#pragma unroll
        for (int k = 0; k < 4; ++k) {
            acc[2 * k]     += w0 * __uint_as_float(u0[k] << 16);
            acc[2 * k + 1] += w0 * __uint_as_float(u0[k] & 0xffff0000u);
            acc[2 * k]     += w1 * __uint_as_float(u1[k] << 16);
            acc[2 * k + 1] += w1 * __uint_as_float(u1[k] & 0xffff0000u);
            acc[2 * k]     += w2 * __uint_as_float(u2[k] << 16);
            acc[2 * k + 1] += w2 * __uint_as_float(u2[k] & 0xffff0000u);
            acc[2 * k]     += w3 * __uint_as_float(u3[k] << 16);
            acc[2 * k + 1] += w3 * __uint_as_float(u3[k] & 0xffff0000u);
        }
    }
    // tail (0-3 edges)
    for (; i < end; ++i) {
        int s = colsrc[i];
        float ev = as[(size_t)s * H + head] + adh;
        ev = (ev > 0.f) ? ev : NEG_SLOPE * ev;
        float wgt = __expf(ev);
        den += wgt;
        uint4 a = *(const uint4*)(hb + (size_t)s * 128 + cl * 8);
        unsigned int u[4] = {a.x, a.y, a.z, a.w};
#pragma unroll
        for (int k = 0; k < 4; ++k) {
            acc[2 * k]     += wgt * __uint_as_float(u[k] << 16);
            acc[2 * k + 1] += wgt * __uint_as_float(u[k] & 0xffff0000u);
        }
    }

    float inv = 1.0f / den;
    float r[8];
#pragma unroll
    for (int k = 0; k < 8; ++k) {
        r[k] = acc[k] * inv + bias[cl * 8 + k];
        if (OBF) r[k] = (r[k] > 0.f) ? r[k] : expm1f(r[k]);  // ELU (layer 1)
    }
    if (OBF) {
        unsigned short o[8];
#pragma unroll
        for (int k = 0; k < 8; ++k) o[k] = f2bf(r[k]);
        *(uint4*)((unsigned short*)outv + (size_t)node * 128 + cl * 8) = *(uint4*)o;
    } else {
        float4* p = (float4*)((float*)outv + (size_t)node * 128 + cl * 8);
        p[0] = make_float4(r[0], r[1], r[2], r[3]);
        p[1] = make_float4(r[4], r[5], r[6], r[7]);
    }
}

// ---------------- launch ----------------

extern "C" void kernel_launch(void* const* d_in, const int* in_sizes, int n_in,
                              void* d_out, int out_size, void* d_ws, size_t ws_size,
                              hipStream_t stream) {
    const float* x    = (const float*)d_in[0];
    const int*   ei   = (const int*)d_in[1];
    const float* W1   = (const float*)d_in[2];
    const float* a_s1 = (const float*)d_in[3];
    const float* a_d1 = (const float*)d_in[4];
    const float* b1   = (const float*)d_in[5];
    const float* W2   = (const float*)d_in[6];
    const float* a_s2 = (const float*)d_in[7];
    const float* a_d2 = (const float*)d_in[8];
    const float* b2   = (const float*)d_in[9];

    const int n  = in_sizes[0] / 128;
    const int e  = in_sizes[1] / 2;
    const int en = e + n;
    const int nbuck = (n + 255) >> 8;
    const int echunks = (en + 2047) / 2048;

    char* ws = (char*)d_ws;
    size_t off = 0;
    auto alloc = [&](size_t bytes) -> void* {
        void* p = ws + off;
        off += (bytes + 255) & ~(size_t)255;
        return p;
    };
    unsigned short* hb   = (unsigned short*)alloc((size_t)n * 128 * 2);
    unsigned short* hmid = (unsigned short*)alloc((size_t)n * 128 * 2);
    float* as1    = (float*)alloc((size_t)n * 8 * 4);
    float* ad1    = (float*)alloc((size_t)n * 8 * 4);
    float* as2    = (float*)alloc((size_t)n * 4);
    float* ad2    = (float*)alloc((size_t)n * 4);
    int*   rowptr = (int*)alloc((size_t)(n + 1) * 4);
    int*   colsrc = (int*)alloc((size_t)en * 4);
    unsigned int* gpair = (unsigned int*)alloc((size_t)nbuck * BCAP * 4);
    int*   gcursor= (int*)alloc(256 * 4);
    unsigned short* Wf1 = (unsigned short*)alloc(4 * 9 * 64 * 8 * 2);
    unsigned short* Wf2 = (unsigned short*)alloc(4 * 9 * 64 * 8 * 2);

    // prep weights + zero cursors + rowptr[n] (one launch)
    prep_w_kernel<<<9, 256, 0, stream>>>(W1, a_s1, a_d1, Wf1, W2, a_s2, a_d2, Wf2,
                                         gcursor, rowptr, n, en);
    // CSR build: scatter into bins, then per-bucket local CSR
    scatter_kernel<<<echunks, 256, 0, stream>>>(ei, e, n, gcursor, gpair);
    bucket_csr_kernel<<<nbuck, 256, 0, stream>>>(gpair, gcursor, rowptr, colsrc, n);

    int gemm_grid = (n + 63) / 64;
    int node_grid = (n + 15) / 16;

    // layer 1
    gemm_mfma_kernel<8, false><<<gemm_grid, 256, 0, stream>>>(x, Wf1, hb, as1, ad1, n);
    agg_kernel<8, 1><<<node_grid, 256, 0, stream>>>(rowptr, colsrc, hb, as1, ad1, b1, hmid, n);

    // layer 2
    gemm_mfma_kernel<1, true><<<gemm_grid, 256, 0, stream>>>(hmid, Wf2, hb, as2, ad2, n);
    agg_kernel<1, 0><<<node_grid, 256, 0, stream>>>(rowptr, colsrc, hb, as2, ad2, b2, d_out, n);

    (void)n_in; (void)out_size; (void)ws_size;
}